// Round 1
// baseline (1430.148 us; speedup 1.0000x reference)
//
#include <hip/hip_runtime.h>
#include <math.h>

#define D 128

// Read a scalar that might be int32/int64 (small value) or float32.
__device__ __forceinline__ float int_or_float(const void* p) {
    int iv = *(const int*)p;
    if (iv > -1000000 && iv < 1000000) return (float)iv;
    return __int_as_float(iv);
}

// --- kernel 1: in-degree count (int atomics, HW-native) ---
__global__ __launch_bounds__(256) void k_deg(const int* __restrict__ dst,
                                             int* __restrict__ deg, int E) {
    int i = blockIdx.x * 256 + threadIdx.x;
    if (i < E) atomicAdd(&deg[dst[i]], 1);
}

// --- kernel 2: dinv = rsqrt(max(deg,1)), in place over deg ---
__global__ __launch_bounds__(256) void k_dinv(int* dd, int n) {
    int i = blockIdx.x * 256 + threadIdx.x;
    if (i < n) {
        int d = dd[i];
        if (d < 1) d = 1;
        ((float*)dd)[i] = rsqrtf((float)d);
    }
}

// --- kernel 3: scatter SpMM: hacc[dst] += x[src] * dinv[src] ---
// 32 lanes per edge, one float4 per lane -> 512B contiguous row reads.
__global__ __launch_bounds__(256) void k_scatter(const float4* __restrict__ x4,
                                                 const int* __restrict__ src,
                                                 const int* __restrict__ dst,
                                                 const float* __restrict__ dinv,
                                                 float* hacc, int E) {
    int idx = blockIdx.x * 256 + threadIdx.x;
    int e = idx >> 5;
    if (e >= E) return;
    int q = idx & 31;
    int s = src[e];
    int t = dst[e];
    float sc = dinv[s];
    float4 v = x4[(size_t)s * (D / 4) + q];
    float* h = hacc + (size_t)t * D + q * 4;
    unsafeAtomicAdd(h + 0, v.x * sc);
    unsafeAtomicAdd(h + 1, v.y * sc);
    unsafeAtomicAdd(h + 2, v.z * sc);
    unsafeAtomicAdd(h + 3, v.w * sc);
}

// --- kernel 4: fused epilogue ---
// io holds hacc on entry, final out on exit (in place; block stages its own
// 32 rows in LDS before overwriting them).
// support = (1-alpha)*hacc*dinv + alpha*h0
// out     = theta*(support @ W) + (1-theta)*support + x
__global__ __launch_bounds__(256) void k_final(float* io,
                                               const float* __restrict__ dinv,
                                               const float* __restrict__ h0,
                                               const float* __restrict__ x,
                                               const float* __restrict__ W,
                                               const float* __restrict__ lamda_p,
                                               const float* __restrict__ alpha_p,
                                               const void* __restrict__ l_p,
                                               int n) {
    __shared__ float sW[D * D];       // 64 KB, W[k][c]
    __shared__ float sSup[32][D];     // 16 KB, support tile
    const int t = threadIdx.x;

    // stage W (float4-coalesced)
    {
        const float4* W4 = (const float4*)W;
        float4* sW4 = (float4*)sW;
        #pragma unroll
        for (int i = 0; i < (D * D / 4) / 256; ++i)
            sW4[i * 256 + t] = W4[i * 256 + t];
    }

    const float alpha = *alpha_p;
    const float lamda = *lamda_p;
    const float lf = int_or_float(l_p);
    const float theta = logf(lamda / lf + 1.0f);
    const float omt = 1.0f - theta;
    const float oma = 1.0f - alpha;

    const int base = blockIdx.x * 32;

    // stage support tile: 32 rows x 128 cols = 1024 float4 loads
    {
        const float4* hacc4 = (const float4*)io;
        const float4* h04 = (const float4*)h0;
        #pragma unroll
        for (int i = 0; i < 4; ++i) {
            int v = i * 256 + t;      // 0..1023
            int tr = v >> 5;          // tile row
            int q = v & 31;           // float4 index in row
            int r = base + tr;
            float4 sup = make_float4(0.f, 0.f, 0.f, 0.f);
            if (r < n) {
                float ca = oma * dinv[r];
                float4 a = hacc4[(size_t)r * (D / 4) + q];
                float4 b = h04[(size_t)r * (D / 4) + q];
                sup.x = ca * a.x + alpha * b.x;
                sup.y = ca * a.y + alpha * b.y;
                sup.z = ca * a.z + alpha * b.z;
                sup.w = ca * a.w + alpha * b.w;
            }
            *(float4*)&sSup[tr][q * 4] = sup;
        }
    }
    __syncthreads();

    // register-tiled GEMM: thread owns 4 rows x 4 cols
    const int cg = t & 31;   // column group (4 cols)
    const int rb = t >> 5;   // 0..7 row block
    float acc[4][4] = {};
    const float4* sW4 = (const float4*)sW;
    #pragma unroll 4
    for (int k = 0; k < D; ++k) {
        float4 w = sW4[k * 32 + cg];
        #pragma unroll
        for (int j = 0; j < 4; ++j) {
            float s = sSup[rb * 4 + j][k];   // broadcast within 32-lane group
            acc[j][0] += s * w.x;
            acc[j][1] += s * w.y;
            acc[j][2] += s * w.z;
            acc[j][3] += s * w.w;
        }
    }

    // epilogue + in-place store
    #pragma unroll
    for (int j = 0; j < 4; ++j) {
        int tr = rb * 4 + j;
        int r = base + tr;
        if (r < n) {
            float4 xi = ((const float4*)x)[(size_t)r * (D / 4) + cg];
            float4 sp = *(const float4*)&sSup[tr][cg * 4];
            float4 o;
            o.x = theta * acc[j][0] + omt * sp.x + xi.x;
            o.y = theta * acc[j][1] + omt * sp.y + xi.y;
            o.z = theta * acc[j][2] + omt * sp.z + xi.z;
            o.w = theta * acc[j][3] + omt * sp.w + xi.w;
            ((float4*)io)[(size_t)r * (D / 4) + cg] = o;
        }
    }
}

extern "C" void kernel_launch(void* const* d_in, const int* in_sizes, int n_in,
                              void* d_out, int out_size, void* d_ws, size_t ws_size,
                              hipStream_t stream) {
    const float* x = (const float*)d_in[0];
    const int* esrc = (const int*)d_in[1];
    const int* edst = (const int*)d_in[2];
    const float* h0 = (const float*)d_in[3];
    const float* W = (const float*)d_in[4];
    const float* lamda_p = (const float*)d_in[5];
    const float* alpha_p = (const float*)d_in[6];
    const void* l_p = d_in[7];

    const int E = in_sizes[1];
    const int n = in_sizes[0] / D;

    float* hacc = (float*)d_out;      // accumulate SpMM directly in d_out
    int* deg = (int*)d_ws;            // N ints; becomes dinv (float) in place

    hipMemsetAsync(d_out, 0, (size_t)n * D * sizeof(float), stream);
    hipMemsetAsync(d_ws, 0, (size_t)n * sizeof(int), stream);

    k_deg<<<(E + 255) / 256, 256, 0, stream>>>(edst, deg, E);
    k_dinv<<<(n + 255) / 256, 256, 0, stream>>>(deg, n);
    k_scatter<<<(E * 32 + 255) / 256, 256, 0, stream>>>(
        (const float4*)x, esrc, edst, (const float*)d_ws, hacc, E);
    k_final<<<(n + 31) / 32, 256, 0, stream>>>(
        (float*)d_out, (const float*)d_ws, h0, x, W, lamda_p, alpha_p, l_p, n);
}

// Round 2
// 204.862 us; speedup vs baseline: 6.9810x; 6.9810x over previous
//
#include <hip/hip_runtime.h>
#include <math.h>

#define D 128

__device__ __forceinline__ float int_or_float(const void* p) {
    int iv = *(const int*)p;
    if (iv > -1000000 && iv < 1000000) return (float)iv;
    return __int_as_float(iv);
}

// --- in-degree count ---
__global__ __launch_bounds__(256) void k_deg(const int* __restrict__ dst,
                                             int* __restrict__ deg, int E) {
    int i = blockIdx.x * 256 + threadIdx.x;
    if (i < E) atomicAdd(&deg[dst[i]], 1);
}

// --- dinv = rsqrt(max(deg,1)), in place over deg (run AFTER scans read deg) ---
__global__ __launch_bounds__(256) void k_dinv(int* dd, int n) {
    int i = blockIdx.x * 256 + threadIdx.x;
    if (i < n) {
        int d = dd[i];
        if (d < 1) d = 1;
        ((float*)dd)[i] = rsqrtf((float)d);
    }
}

// --- scan step 1: per-1024-chunk sums ---
__global__ __launch_bounds__(256) void k_scan1(const int* __restrict__ deg,
                                               int* __restrict__ bsum, int n) {
    __shared__ int red[256];
    int b = blockIdx.x, t = threadIdx.x;
    int base = b * 1024;
    int s = 0;
    #pragma unroll
    for (int i = 0; i < 4; ++i) {
        int idx = base + i * 256 + t;
        if (idx < n) s += deg[idx];
    }
    red[t] = s;
    __syncthreads();
    for (int k = 128; k > 0; k >>= 1) {
        if (t < k) red[t] += red[t + k];
        __syncthreads();
    }
    if (t == 0) bsum[b] = red[0];
}

// --- scan step 2: serial scan of chunk sums (nb <= 64) + offsets[n] = E ---
__global__ void k_scan2(const int* __restrict__ bsum, int* __restrict__ boff,
                        int* __restrict__ offsets, int nb, int n) {
    if (threadIdx.x == 0) {
        int acc = 0;
        for (int i = 0; i < nb; ++i) { boff[i] = acc; acc += bsum[i]; }
        offsets[n] = acc;
    }
}

// --- scan step 3: exclusive scan within chunk + chunk offset -> offsets, cursor ---
__global__ __launch_bounds__(256) void k_scan3(const int* __restrict__ deg,
                                               const int* __restrict__ boff,
                                               int* __restrict__ offsets,
                                               int* __restrict__ cursor, int n) {
    __shared__ int ls[256];
    int b = blockIdx.x, t = threadIdx.x;
    int base = b * 1024 + t * 4;
    int v[4];
    #pragma unroll
    for (int i = 0; i < 4; ++i) v[i] = (base + i < n) ? deg[base + i] : 0;
    int mysum = v[0] + v[1] + v[2] + v[3];
    ls[t] = mysum;
    __syncthreads();
    // Hillis-Steele inclusive scan over 256 thread-sums
    for (int k = 1; k < 256; k <<= 1) {
        int add = (t >= k) ? ls[t - k] : 0;
        __syncthreads();
        ls[t] += add;
        __syncthreads();
    }
    int p = boff[b] + ls[t] - mysum;   // exclusive prefix for this thread
    #pragma unroll
    for (int i = 0; i < 4; ++i) {
        if (base + i < n) { offsets[base + i] = p; cursor[base + i] = p; }
        p += v[i];
    }
}

// --- CSR fill: csr_src grouped by dst ---
__global__ __launch_bounds__(256) void k_csr(const int* __restrict__ src,
                                             const int* __restrict__ dst,
                                             int* __restrict__ cursor,
                                             int* __restrict__ csr_src, int E) {
    int i = blockIdx.x * 256 + threadIdx.x;
    if (i < E) {
        int pos = atomicAdd(&cursor[dst[i]], 1);
        csr_src[pos] = src[i];
    }
}

// --- pull-gather SpMM: hacc[r] = sum_{e in row r} x[src[e]] * dinv[src[e]] ---
// 32 lanes per dst row, one float4 per lane.
__global__ __launch_bounds__(256) void k_gather(const float4* __restrict__ x4,
                                                const int* __restrict__ csr_src,
                                                const int* __restrict__ offsets,
                                                const float* __restrict__ dinv,
                                                float4* __restrict__ hacc, int n) {
    int idx = blockIdx.x * 256 + threadIdx.x;
    int r = idx >> 5;
    if (r >= n) return;
    int q = idx & 31;
    int e0 = offsets[r], e1 = offsets[r + 1];
    float4 acc = make_float4(0.f, 0.f, 0.f, 0.f);
    for (int e = e0; e < e1; ++e) {
        int s = csr_src[e];
        float sc = dinv[s];
        float4 v = x4[(size_t)s * (D / 4) + q];
        acc.x += v.x * sc;
        acc.y += v.y * sc;
        acc.z += v.z * sc;
        acc.w += v.w * sc;
    }
    hacc[(size_t)r * (D / 4) + q] = acc;
}

// --- legacy atomic scatter (fallback only, if ws too small for CSR) ---
__global__ __launch_bounds__(256) void k_scatter(const float4* __restrict__ x4,
                                                 const int* __restrict__ src,
                                                 const int* __restrict__ dst,
                                                 const float* __restrict__ dinv,
                                                 float* hacc, int E) {
    int idx = blockIdx.x * 256 + threadIdx.x;
    int e = idx >> 5;
    if (e >= E) return;
    int q = idx & 31;
    int s = src[e];
    int t = dst[e];
    float sc = dinv[s];
    float4 v = x4[(size_t)s * (D / 4) + q];
    float* h = hacc + (size_t)t * D + q * 4;
    unsafeAtomicAdd(h + 0, v.x * sc);
    unsafeAtomicAdd(h + 1, v.y * sc);
    unsafeAtomicAdd(h + 2, v.z * sc);
    unsafeAtomicAdd(h + 3, v.w * sc);
}

// --- fused epilogue (in place over io = hacc -> out) ---
__global__ __launch_bounds__(256) void k_final(float* io,
                                               const float* __restrict__ dinv,
                                               const float* __restrict__ h0,
                                               const float* __restrict__ x,
                                               const float* __restrict__ W,
                                               const float* __restrict__ lamda_p,
                                               const float* __restrict__ alpha_p,
                                               const void* __restrict__ l_p,
                                               int n) {
    __shared__ float sW[D * D];
    __shared__ float sSup[32][D];
    const int t = threadIdx.x;

    {
        const float4* W4 = (const float4*)W;
        float4* sW4 = (float4*)sW;
        #pragma unroll
        for (int i = 0; i < (D * D / 4) / 256; ++i)
            sW4[i * 256 + t] = W4[i * 256 + t];
    }

    const float alpha = *alpha_p;
    const float lamda = *lamda_p;
    const float lf = int_or_float(l_p);
    const float theta = logf(lamda / lf + 1.0f);
    const float omt = 1.0f - theta;
    const float oma = 1.0f - alpha;

    const int base = blockIdx.x * 32;

    {
        const float4* hacc4 = (const float4*)io;
        const float4* h04 = (const float4*)h0;
        #pragma unroll
        for (int i = 0; i < 4; ++i) {
            int v = i * 256 + t;
            int tr = v >> 5;
            int q = v & 31;
            int r = base + tr;
            float4 sup = make_float4(0.f, 0.f, 0.f, 0.f);
            if (r < n) {
                float ca = oma * dinv[r];
                float4 a = hacc4[(size_t)r * (D / 4) + q];
                float4 b = h04[(size_t)r * (D / 4) + q];
                sup.x = ca * a.x + alpha * b.x;
                sup.y = ca * a.y + alpha * b.y;
                sup.z = ca * a.z + alpha * b.z;
                sup.w = ca * a.w + alpha * b.w;
            }
            *(float4*)&sSup[tr][q * 4] = sup;
        }
    }
    __syncthreads();

    const int cg = t & 31;
    const int rb = t >> 5;
    float acc[4][4] = {};
    const float4* sW4 = (const float4*)sW;
    #pragma unroll 4
    for (int k = 0; k < D; ++k) {
        float4 w = sW4[k * 32 + cg];
        #pragma unroll
        for (int j = 0; j < 4; ++j) {
            float s = sSup[rb * 4 + j][k];
            acc[j][0] += s * w.x;
            acc[j][1] += s * w.y;
            acc[j][2] += s * w.z;
            acc[j][3] += s * w.w;
        }
    }

    #pragma unroll
    for (int j = 0; j < 4; ++j) {
        int tr = rb * 4 + j;
        int r = base + tr;
        if (r < n) {
            float4 xi = ((const float4*)x)[(size_t)r * (D / 4) + cg];
            float4 sp = *(const float4*)&sSup[tr][cg * 4];
            float4 o;
            o.x = theta * acc[j][0] + omt * sp.x + xi.x;
            o.y = theta * acc[j][1] + omt * sp.y + xi.y;
            o.z = theta * acc[j][2] + omt * sp.z + xi.z;
            o.w = theta * acc[j][3] + omt * sp.w + xi.w;
            ((float4*)io)[(size_t)r * (D / 4) + cg] = o;
        }
    }
}

extern "C" void kernel_launch(void* const* d_in, const int* in_sizes, int n_in,
                              void* d_out, int out_size, void* d_ws, size_t ws_size,
                              hipStream_t stream) {
    const float* x = (const float*)d_in[0];
    const int* esrc = (const int*)d_in[1];
    const int* edst = (const int*)d_in[2];
    const float* h0 = (const float*)d_in[3];
    const float* W = (const float*)d_in[4];
    const float* lamda_p = (const float*)d_in[5];
    const float* alpha_p = (const float*)d_in[6];
    const void* l_p = d_in[7];

    const int E = in_sizes[1];
    const int n = in_sizes[0] / D;
    const int nb = (n + 1023) / 1024;   // scan chunks

    // ws layout (16B-aligned slots)
    char* w = (char*)d_ws;
    size_t o_deg  = 0;                                   // n ints -> becomes dinv
    size_t o_off  = (o_deg + (size_t)n * 4 + 15) & ~15ull;       // n+1 ints
    size_t o_cur  = (o_off + (size_t)(n + 1) * 4 + 15) & ~15ull; // n ints
    size_t o_bs   = (o_cur + (size_t)n * 4 + 15) & ~15ull;       // nb ints
    size_t o_bo   = (o_bs + (size_t)nb * 4 + 15) & ~15ull;       // nb ints
    size_t o_csr  = (o_bo + (size_t)nb * 4 + 15) & ~15ull;       // E ints
    size_t needed = o_csr + (size_t)E * 4;

    int* deg = (int*)(w + o_deg);
    float* dinv = (float*)(w + o_deg);

    hipMemsetAsync(deg, 0, (size_t)n * sizeof(int), stream);
    k_deg<<<(E + 255) / 256, 256, 0, stream>>>(edst, deg, E);

    if (ws_size >= needed && nb <= 1024) {
        int* offsets = (int*)(w + o_off);
        int* cursor  = (int*)(w + o_cur);
        int* bsum    = (int*)(w + o_bs);
        int* boff    = (int*)(w + o_bo);
        int* csr_src = (int*)(w + o_csr);

        k_scan1<<<nb, 256, 0, stream>>>(deg, bsum, n);
        k_scan2<<<1, 64, 0, stream>>>(bsum, boff, offsets, nb, n);
        k_scan3<<<nb, 256, 0, stream>>>(deg, boff, offsets, cursor, n);
        k_dinv<<<(n + 255) / 256, 256, 0, stream>>>(deg, n);
        k_csr<<<(E + 255) / 256, 256, 0, stream>>>(esrc, edst, cursor, csr_src, E);
        k_gather<<<((size_t)n * 32 + 255) / 256, 256, 0, stream>>>(
            (const float4*)x, csr_src, offsets, dinv, (float4*)d_out, n);
    } else {
        // fallback: atomic scatter into zeroed d_out
        k_dinv<<<(n + 255) / 256, 256, 0, stream>>>(deg, n);
        hipMemsetAsync(d_out, 0, (size_t)n * D * sizeof(float), stream);
        k_scatter<<<((size_t)E * 32 + 255) / 256, 256, 0, stream>>>(
            (const float4*)x, esrc, edst, dinv, (float*)d_out, E);
    }

    k_final<<<(n + 31) / 32, 256, 0, stream>>>(
        (float*)d_out, dinv, h0, x, W, lamda_p, alpha_p, l_p, n);
}

// Round 3
// 195.758 us; speedup vs baseline: 7.3057x; 1.0465x over previous
//
#include <hip/hip_runtime.h>
#include <math.h>

#define D 128

__device__ __forceinline__ float int_or_float(const void* p) {
    int iv = *(const int*)p;
    if (iv > -1000000 && iv < 1000000) return (float)iv;
    return __int_as_float(iv);
}

// --- in-degree count ---
__global__ __launch_bounds__(256) void k_deg(const int* __restrict__ dst,
                                             int* __restrict__ deg, int E) {
    int i = blockIdx.x * 256 + threadIdx.x;
    if (i < E) atomicAdd(&deg[dst[i]], 1);
}

// --- dinv standalone (fallback path only) ---
__global__ __launch_bounds__(256) void k_dinv(int* dd, int n) {
    int i = blockIdx.x * 256 + threadIdx.x;
    if (i < n) {
        int d = dd[i];
        if (d < 1) d = 1;
        ((float*)dd)[i] = rsqrtf((float)d);
    }
}

// --- scan step 1: per-1024-chunk sums ---
__global__ __launch_bounds__(256) void k_scan1(const int* __restrict__ deg,
                                               int* __restrict__ bsum, int n) {
    __shared__ int red[256];
    int b = blockIdx.x, t = threadIdx.x;
    int base = b * 1024;
    int s = 0;
    #pragma unroll
    for (int i = 0; i < 4; ++i) {
        int idx = base + i * 256 + t;
        if (idx < n) s += deg[idx];
    }
    red[t] = s;
    __syncthreads();
    for (int k = 128; k > 0; k >>= 1) {
        if (t < k) red[t] += red[t + k];
        __syncthreads();
    }
    if (t == 0) bsum[b] = red[0];
}

// --- scan step 2: serial scan of chunk sums + offsets[n] = E ---
__global__ void k_scan2(const int* __restrict__ bsum, int* __restrict__ boff,
                        int* __restrict__ offsets, int nb, int n) {
    if (threadIdx.x == 0) {
        int acc = 0;
        for (int i = 0; i < nb; ++i) { boff[i] = acc; acc += bsum[i]; }
        offsets[n] = acc;
    }
}

// --- scan step 3: exclusive scan within chunk -> offsets, cursor; ALSO
//     converts deg -> dinv in place (each element owned by one thread). ---
__global__ __launch_bounds__(256) void k_scan3(int* __restrict__ deg,
                                               const int* __restrict__ boff,
                                               int* __restrict__ offsets,
                                               int* __restrict__ cursor, int n) {
    __shared__ int ls[256];
    int b = blockIdx.x, t = threadIdx.x;
    int base = b * 1024 + t * 4;
    int v[4];
    #pragma unroll
    for (int i = 0; i < 4; ++i) v[i] = (base + i < n) ? deg[base + i] : 0;
    int mysum = v[0] + v[1] + v[2] + v[3];
    ls[t] = mysum;
    __syncthreads();
    for (int k = 1; k < 256; k <<= 1) {
        int add = (t >= k) ? ls[t - k] : 0;
        __syncthreads();
        ls[t] += add;
        __syncthreads();
    }
    int p = boff[b] + ls[t] - mysum;
    #pragma unroll
    for (int i = 0; i < 4; ++i) {
        if (base + i < n) {
            offsets[base + i] = p;
            cursor[base + i] = p;
            int d = v[i] < 1 ? 1 : v[i];
            ((float*)deg)[base + i] = rsqrtf((float)d);   // deg -> dinv in place
        }
        p += v[i];
    }
}

// --- CSR fill: csr_src grouped by dst ---
__global__ __launch_bounds__(256) void k_csr(const int* __restrict__ src,
                                             const int* __restrict__ dst,
                                             int* __restrict__ cursor,
                                             int* __restrict__ csr_src, int E) {
    int i = blockIdx.x * 256 + threadIdx.x;
    if (i < E) {
        int pos = atomicAdd(&cursor[dst[i]], 1);
        csr_src[pos] = src[i];
    }
}

// --- pull-gather SpMM, 4x unrolled for MLP ---
// 32 lanes per dst row, one float4 per lane; 4 independent source rows in
// flight per iteration, 4 separate accumulators to break FMA chains.
__global__ __launch_bounds__(256) void k_gather(const float4* __restrict__ x4,
                                                const int* __restrict__ csr_src,
                                                const int* __restrict__ offsets,
                                                const float* __restrict__ dinv,
                                                float4* __restrict__ hacc, int n) {
    int idx = blockIdx.x * 256 + threadIdx.x;
    int r = idx >> 5;
    if (r >= n) return;
    int q = idx & 31;
    int e0 = offsets[r], e1 = offsets[r + 1];
    float4 a0 = make_float4(0.f, 0.f, 0.f, 0.f);
    float4 a1 = make_float4(0.f, 0.f, 0.f, 0.f);
    float4 a2 = make_float4(0.f, 0.f, 0.f, 0.f);
    float4 a3 = make_float4(0.f, 0.f, 0.f, 0.f);
    int e = e0;
    for (; e + 4 <= e1; e += 4) {
        int s0 = csr_src[e + 0];
        int s1 = csr_src[e + 1];
        int s2 = csr_src[e + 2];
        int s3 = csr_src[e + 3];
        float c0 = dinv[s0], c1 = dinv[s1], c2 = dinv[s2], c3 = dinv[s3];
        float4 v0 = x4[(size_t)s0 * (D / 4) + q];
        float4 v1 = x4[(size_t)s1 * (D / 4) + q];
        float4 v2 = x4[(size_t)s2 * (D / 4) + q];
        float4 v3 = x4[(size_t)s3 * (D / 4) + q];
        a0.x += v0.x * c0; a0.y += v0.y * c0; a0.z += v0.z * c0; a0.w += v0.w * c0;
        a1.x += v1.x * c1; a1.y += v1.y * c1; a1.z += v1.z * c1; a1.w += v1.w * c1;
        a2.x += v2.x * c2; a2.y += v2.y * c2; a2.z += v2.z * c2; a2.w += v2.w * c2;
        a3.x += v3.x * c3; a3.y += v3.y * c3; a3.z += v3.z * c3; a3.w += v3.w * c3;
    }
    for (; e < e1; ++e) {
        int s = csr_src[e];
        float c = dinv[s];
        float4 v = x4[(size_t)s * (D / 4) + q];
        a0.x += v.x * c; a0.y += v.y * c; a0.z += v.z * c; a0.w += v.w * c;
    }
    float4 acc;
    acc.x = (a0.x + a1.x) + (a2.x + a3.x);
    acc.y = (a0.y + a1.y) + (a2.y + a3.y);
    acc.z = (a0.z + a1.z) + (a2.z + a3.z);
    acc.w = (a0.w + a1.w) + (a2.w + a3.w);
    hacc[(size_t)r * (D / 4) + q] = acc;
}

// --- legacy atomic scatter (fallback only) ---
__global__ __launch_bounds__(256) void k_scatter(const float4* __restrict__ x4,
                                                 const int* __restrict__ src,
                                                 const int* __restrict__ dst,
                                                 const float* __restrict__ dinv,
                                                 float* hacc, int E) {
    int idx = blockIdx.x * 256 + threadIdx.x;
    int e = idx >> 5;
    if (e >= E) return;
    int q = idx & 31;
    int s = src[e];
    int t = dst[e];
    float sc = dinv[s];
    float4 v = x4[(size_t)s * (D / 4) + q];
    float* h = hacc + (size_t)t * D + q * 4;
    unsafeAtomicAdd(h + 0, v.x * sc);
    unsafeAtomicAdd(h + 1, v.y * sc);
    unsafeAtomicAdd(h + 2, v.z * sc);
    unsafeAtomicAdd(h + 3, v.w * sc);
}

// --- fused epilogue (in place over io = hacc -> out) ---
__global__ __launch_bounds__(256) void k_final(float* io,
                                               const float* __restrict__ dinv,
                                               const float* __restrict__ h0,
                                               const float* __restrict__ x,
                                               const float* __restrict__ W,
                                               const float* __restrict__ lamda_p,
                                               const float* __restrict__ alpha_p,
                                               const void* __restrict__ l_p,
                                               int n) {
    __shared__ float sW[D * D];
    __shared__ float sSup[32][D];
    const int t = threadIdx.x;

    {
        const float4* W4 = (const float4*)W;
        float4* sW4 = (float4*)sW;
        #pragma unroll
        for (int i = 0; i < (D * D / 4) / 256; ++i)
            sW4[i * 256 + t] = W4[i * 256 + t];
    }

    const float alpha = *alpha_p;
    const float lamda = *lamda_p;
    const float lf = int_or_float(l_p);
    const float theta = logf(lamda / lf + 1.0f);
    const float omt = 1.0f - theta;
    const float oma = 1.0f - alpha;

    const int base = blockIdx.x * 32;

    {
        const float4* hacc4 = (const float4*)io;
        const float4* h04 = (const float4*)h0;
        #pragma unroll
        for (int i = 0; i < 4; ++i) {
            int v = i * 256 + t;
            int tr = v >> 5;
            int q = v & 31;
            int r = base + tr;
            float4 sup = make_float4(0.f, 0.f, 0.f, 0.f);
            if (r < n) {
                float ca = oma * dinv[r];
                float4 a = hacc4[(size_t)r * (D / 4) + q];
                float4 b = h04[(size_t)r * (D / 4) + q];
                sup.x = ca * a.x + alpha * b.x;
                sup.y = ca * a.y + alpha * b.y;
                sup.z = ca * a.z + alpha * b.z;
                sup.w = ca * a.w + alpha * b.w;
            }
            *(float4*)&sSup[tr][q * 4] = sup;
        }
    }
    __syncthreads();

    const int cg = t & 31;
    const int rb = t >> 5;
    float acc[4][4] = {};
    const float4* sW4 = (const float4*)sW;
    #pragma unroll 4
    for (int k = 0; k < D; ++k) {
        float4 w = sW4[k * 32 + cg];
        #pragma unroll
        for (int j = 0; j < 4; ++j) {
            float s = sSup[rb * 4 + j][k];
            acc[j][0] += s * w.x;
            acc[j][1] += s * w.y;
            acc[j][2] += s * w.z;
            acc[j][3] += s * w.w;
        }
    }

    #pragma unroll
    for (int j = 0; j < 4; ++j) {
        int tr = rb * 4 + j;
        int r = base + tr;
        if (r < n) {
            float4 xi = ((const float4*)x)[(size_t)r * (D / 4) + cg];
            float4 sp = *(const float4*)&sSup[tr][cg * 4];
            float4 o;
            o.x = theta * acc[j][0] + omt * sp.x + xi.x;
            o.y = theta * acc[j][1] + omt * sp.y + xi.y;
            o.z = theta * acc[j][2] + omt * sp.z + xi.z;
            o.w = theta * acc[j][3] + omt * sp.w + xi.w;
            ((float4*)io)[(size_t)r * (D / 4) + cg] = o;
        }
    }
}

extern "C" void kernel_launch(void* const* d_in, const int* in_sizes, int n_in,
                              void* d_out, int out_size, void* d_ws, size_t ws_size,
                              hipStream_t stream) {
    const float* x = (const float*)d_in[0];
    const int* esrc = (const int*)d_in[1];
    const int* edst = (const int*)d_in[2];
    const float* h0 = (const float*)d_in[3];
    const float* W = (const float*)d_in[4];
    const float* lamda_p = (const float*)d_in[5];
    const float* alpha_p = (const float*)d_in[6];
    const void* l_p = d_in[7];

    const int E = in_sizes[1];
    const int n = in_sizes[0] / D;
    const int nb = (n + 1023) / 1024;

    char* w = (char*)d_ws;
    size_t o_deg  = 0;
    size_t o_off  = (o_deg + (size_t)n * 4 + 15) & ~15ull;
    size_t o_cur  = (o_off + (size_t)(n + 1) * 4 + 15) & ~15ull;
    size_t o_bs   = (o_cur + (size_t)n * 4 + 15) & ~15ull;
    size_t o_bo   = (o_bs + (size_t)nb * 4 + 15) & ~15ull;
    size_t o_csr  = (o_bo + (size_t)nb * 4 + 15) & ~15ull;
    size_t needed = o_csr + (size_t)E * 4;

    int* deg = (int*)(w + o_deg);
    float* dinv = (float*)(w + o_deg);

    hipMemsetAsync(deg, 0, (size_t)n * sizeof(int), stream);
    k_deg<<<(E + 255) / 256, 256, 0, stream>>>(edst, deg, E);

    if (ws_size >= needed && nb <= 1024) {
        int* offsets = (int*)(w + o_off);
        int* cursor  = (int*)(w + o_cur);
        int* bsum    = (int*)(w + o_bs);
        int* boff    = (int*)(w + o_bo);
        int* csr_src = (int*)(w + o_csr);

        k_scan1<<<nb, 256, 0, stream>>>(deg, bsum, n);
        k_scan2<<<1, 64, 0, stream>>>(bsum, boff, offsets, nb, n);
        k_scan3<<<nb, 256, 0, stream>>>(deg, boff, offsets, cursor, n);
        k_csr<<<(E + 255) / 256, 256, 0, stream>>>(esrc, edst, cursor, csr_src, E);
        k_gather<<<((size_t)n * 32 + 255) / 256, 256, 0, stream>>>(
            (const float4*)x, csr_src, offsets, dinv, (float4*)d_out, n);
    } else {
        k_dinv<<<(n + 255) / 256, 256, 0, stream>>>(deg, n);
        hipMemsetAsync(d_out, 0, (size_t)n * D * sizeof(float), stream);
        k_scatter<<<((size_t)E * 32 + 255) / 256, 256, 0, stream>>>(
            (const float4*)x, esrc, edst, dinv, (float*)d_out, E);
    }

    k_final<<<(n + 31) / 32, 256, 0, stream>>>(
        (float*)d_out, dinv, h0, x, W, lamda_p, alpha_p, l_p, n);
}

// Round 4
// 137.711 us; speedup vs baseline: 10.3852x; 1.4215x over previous
//
#include <hip/hip_runtime.h>
#include <math.h>

#define D 128
#define P_MAX 64        // plane capacity (max supported in-degree before overflow path)
#define OCAP 65536      // overflow edge capacity
#define CHUNK 2048      // edges per chunk in k_rank

__device__ __forceinline__ float int_or_float(const void* p) {
    int iv = *(const int*)p;
    if (iv > -1000000 && iv < 1000000) return (float)iv;
    return __int_as_float(iv);
}

__device__ __forceinline__ unsigned bf16_rne(float f) {
    unsigned u = __float_as_uint(f);
    return (u + 0x7fffu + ((u >> 16) & 1u)) >> 16;
}
__device__ __forceinline__ unsigned pack_bf2(float a, float b) {
    return bf16_rne(a) | (bf16_rne(b) << 16);
}

// ============================ TIER-1 kernels =============================

// k_rank: deg count + plane-format CSR in one pass, XCD-sliced.
// Block slice = blockIdx&7 handles only dst with (dst>>4)&7 == slice, so each
// deg/plane cache line is written by blocks of a single slice (one XCD under
// round-robin dispatch) -> lines coalesce in local L2 instead of 64B/4B
// amplified writebacks.
__global__ __launch_bounds__(256) void k_rank(const int* __restrict__ src,
                                              const int* __restrict__ dst,
                                              int* __restrict__ deg,
                                              int* __restrict__ planes,
                                              int* __restrict__ cnt,
                                              int2* __restrict__ opairs,
                                              int E, int n) {
    const int slice = blockIdx.x & 7;
    const int chunk = blockIdx.x >> 3;
    int base = chunk * CHUNK;
    int end = base + CHUNK;
    if (end > E) end = E;
    for (int i = base + threadIdx.x; i < end; i += 256) {
        int t = dst[i];
        if (((t >> 4) & 7) == slice) {
            int s = src[i];
            int rk = atomicAdd(&deg[t], 1);
            if (rk < P_MAX) {
                planes[rk * n + t] = s;
            } else {
                int o = atomicAdd(cnt, 1);
                if (o < OCAP) opairs[o] = make_int2(s, t);
            }
        }
    }
}

// k_scale: xs[r] = bf16(x[r] * dinv[r]); also writes dinv[r].
// 16 threads per row, 8 elems each.
__global__ __launch_bounds__(256) void k_scale(const float4* __restrict__ x4,
                                               const int* __restrict__ deg,
                                               uint4* __restrict__ xs4,
                                               float* __restrict__ dinv, int n) {
    int gid = blockIdx.x * 256 + threadIdx.x;
    int r = gid >> 4;
    if (r >= n) return;
    int q = gid & 15;
    int d = deg[r];
    if (d < 1) d = 1;
    float di = rsqrtf((float)d);
    float4 v0 = x4[(size_t)r * 32 + q * 2];
    float4 v1 = x4[(size_t)r * 32 + q * 2 + 1];
    uint4 o;
    o.x = pack_bf2(v0.x * di, v0.y * di);
    o.y = pack_bf2(v0.z * di, v0.w * di);
    o.z = pack_bf2(v1.x * di, v1.y * di);
    o.w = pack_bf2(v1.z * di, v1.w * di);
    xs4[(size_t)r * 16 + q] = o;
    if (q == 0) dinv[r] = di;
}

__device__ __forceinline__ void acc8(float* a, uint4 v) {
    a[0] += __uint_as_float(v.x << 16);
    a[1] += __uint_as_float(v.x & 0xffff0000u);
    a[2] += __uint_as_float(v.y << 16);
    a[3] += __uint_as_float(v.y & 0xffff0000u);
    a[4] += __uint_as_float(v.z << 16);
    a[5] += __uint_as_float(v.z & 0xffff0000u);
    a[6] += __uint_as_float(v.w << 16);
    a[7] += __uint_as_float(v.w & 0xffff0000u);
}

// k_gather2: pull-gather over plane format. 16 lanes per dst row (uint4 = 8
// bf16 per lane), 4-deep unrolled with independent accumulators for MLP.
__global__ __launch_bounds__(256) void k_gather2(const uint4* __restrict__ xs4,
                                                 const int* __restrict__ planes,
                                                 const int* __restrict__ deg,
                                                 float4* __restrict__ hacc, int n) {
    int gid = blockIdx.x * 256 + threadIdx.x;
    int r = gid >> 4;
    if (r >= n) return;
    int q = gid & 15;
    int d = deg[r];
    if (d > P_MAX) d = P_MAX;
    float a0[8] = {}, a1[8] = {}, a2[8] = {}, a3[8] = {};
    int p = 0;
    for (; p + 4 <= d; p += 4) {
        int s0 = planes[(p + 0) * n + r];
        int s1 = planes[(p + 1) * n + r];
        int s2 = planes[(p + 2) * n + r];
        int s3 = planes[(p + 3) * n + r];
        uint4 v0 = xs4[(size_t)s0 * 16 + q];
        uint4 v1 = xs4[(size_t)s1 * 16 + q];
        uint4 v2 = xs4[(size_t)s2 * 16 + q];
        uint4 v3 = xs4[(size_t)s3 * 16 + q];
        acc8(a0, v0);
        acc8(a1, v1);
        acc8(a2, v2);
        acc8(a3, v3);
    }
    for (; p < d; ++p) {
        int s = planes[p * n + r];
        uint4 v = xs4[(size_t)s * 16 + q];
        acc8(a0, v);
    }
    float4 o0, o1;
    o0.x = (a0[0] + a1[0]) + (a2[0] + a3[0]);
    o0.y = (a0[1] + a1[1]) + (a2[1] + a3[1]);
    o0.z = (a0[2] + a1[2]) + (a2[2] + a3[2]);
    o0.w = (a0[3] + a1[3]) + (a2[3] + a3[3]);
    o1.x = (a0[4] + a1[4]) + (a2[4] + a3[4]);
    o1.y = (a0[5] + a1[5]) + (a2[5] + a3[5]);
    o1.z = (a0[6] + a1[6]) + (a2[6] + a3[6]);
    o1.w = (a0[7] + a1[7]) + (a2[7] + a3[7]);
    hacc[(size_t)r * 32 + q * 2] = o0;
    hacc[(size_t)r * 32 + q * 2 + 1] = o1;
}

// k_oflow: add overflow edges (rank >= P_MAX) into hacc. Normally cnt == 0.
__global__ __launch_bounds__(256) void k_oflow(const int* __restrict__ cnt,
                                               const int2* __restrict__ opairs,
                                               const uint2* __restrict__ xs2,
                                               float* __restrict__ out) {
    int c = *cnt;
    if (c > OCAP) c = OCAP;
    int total = c * 32;
    for (int idx = blockIdx.x * 256 + threadIdx.x; idx < total;
         idx += gridDim.x * 256) {
        int e = idx >> 5, q = idx & 31;
        int2 pr = opairs[e];
        uint2 v = xs2[(size_t)pr.x * 32 + q];
        float* o = out + (size_t)pr.y * D + q * 4;
        unsafeAtomicAdd(o + 0, __uint_as_float(v.x << 16));
        unsafeAtomicAdd(o + 1, __uint_as_float(v.x & 0xffff0000u));
        unsafeAtomicAdd(o + 2, __uint_as_float(v.y << 16));
        unsafeAtomicAdd(o + 3, __uint_as_float(v.y & 0xffff0000u));
    }
}

// ==================== TIER-2 (old CSR path) kernels ======================

__global__ __launch_bounds__(256) void k_deg(const int* __restrict__ dst,
                                             int* __restrict__ deg, int E) {
    int i = blockIdx.x * 256 + threadIdx.x;
    if (i < E) atomicAdd(&deg[dst[i]], 1);
}

__global__ __launch_bounds__(256) void k_dinv(int* dd, int n) {
    int i = blockIdx.x * 256 + threadIdx.x;
    if (i < n) {
        int d = dd[i];
        if (d < 1) d = 1;
        ((float*)dd)[i] = rsqrtf((float)d);
    }
}

__global__ __launch_bounds__(256) void k_scan1(const int* __restrict__ deg,
                                               int* __restrict__ bsum, int n) {
    __shared__ int red[256];
    int b = blockIdx.x, t = threadIdx.x;
    int base = b * 1024;
    int s = 0;
    #pragma unroll
    for (int i = 0; i < 4; ++i) {
        int idx = base + i * 256 + t;
        if (idx < n) s += deg[idx];
    }
    red[t] = s;
    __syncthreads();
    for (int k = 128; k > 0; k >>= 1) {
        if (t < k) red[t] += red[t + k];
        __syncthreads();
    }
    if (t == 0) bsum[b] = red[0];
}

__global__ void k_scan2(const int* __restrict__ bsum, int* __restrict__ boff,
                        int* __restrict__ offsets, int nb, int n) {
    if (threadIdx.x == 0) {
        int acc = 0;
        for (int i = 0; i < nb; ++i) { boff[i] = acc; acc += bsum[i]; }
        offsets[n] = acc;
    }
}

__global__ __launch_bounds__(256) void k_scan3(int* __restrict__ deg,
                                               const int* __restrict__ boff,
                                               int* __restrict__ offsets,
                                               int* __restrict__ cursor, int n) {
    __shared__ int ls[256];
    int b = blockIdx.x, t = threadIdx.x;
    int base = b * 1024 + t * 4;
    int v[4];
    #pragma unroll
    for (int i = 0; i < 4; ++i) v[i] = (base + i < n) ? deg[base + i] : 0;
    int mysum = v[0] + v[1] + v[2] + v[3];
    ls[t] = mysum;
    __syncthreads();
    for (int k = 1; k < 256; k <<= 1) {
        int add = (t >= k) ? ls[t - k] : 0;
        __syncthreads();
        ls[t] += add;
        __syncthreads();
    }
    int p = boff[b] + ls[t] - mysum;
    #pragma unroll
    for (int i = 0; i < 4; ++i) {
        if (base + i < n) {
            offsets[base + i] = p;
            cursor[base + i] = p;
            int d = v[i] < 1 ? 1 : v[i];
            ((float*)deg)[base + i] = rsqrtf((float)d);
        }
        p += v[i];
    }
}

__global__ __launch_bounds__(256) void k_csr(const int* __restrict__ src,
                                             const int* __restrict__ dst,
                                             int* __restrict__ cursor,
                                             int* __restrict__ csr_src, int E) {
    int i = blockIdx.x * 256 + threadIdx.x;
    if (i < E) {
        int pos = atomicAdd(&cursor[dst[i]], 1);
        csr_src[pos] = src[i];
    }
}

__global__ __launch_bounds__(256) void k_gather(const float4* __restrict__ x4,
                                                const int* __restrict__ csr_src,
                                                const int* __restrict__ offsets,
                                                const float* __restrict__ dinv,
                                                float4* __restrict__ hacc, int n) {
    int idx = blockIdx.x * 256 + threadIdx.x;
    int r = idx >> 5;
    if (r >= n) return;
    int q = idx & 31;
    int e0 = offsets[r], e1 = offsets[r + 1];
    float4 a0 = make_float4(0.f, 0.f, 0.f, 0.f);
    float4 a1 = make_float4(0.f, 0.f, 0.f, 0.f);
    float4 a2 = make_float4(0.f, 0.f, 0.f, 0.f);
    float4 a3 = make_float4(0.f, 0.f, 0.f, 0.f);
    int e = e0;
    for (; e + 4 <= e1; e += 4) {
        int s0 = csr_src[e + 0];
        int s1 = csr_src[e + 1];
        int s2 = csr_src[e + 2];
        int s3 = csr_src[e + 3];
        float c0 = dinv[s0], c1 = dinv[s1], c2 = dinv[s2], c3 = dinv[s3];
        float4 v0 = x4[(size_t)s0 * (D / 4) + q];
        float4 v1 = x4[(size_t)s1 * (D / 4) + q];
        float4 v2 = x4[(size_t)s2 * (D / 4) + q];
        float4 v3 = x4[(size_t)s3 * (D / 4) + q];
        a0.x += v0.x * c0; a0.y += v0.y * c0; a0.z += v0.z * c0; a0.w += v0.w * c0;
        a1.x += v1.x * c1; a1.y += v1.y * c1; a1.z += v1.z * c1; a1.w += v1.w * c1;
        a2.x += v2.x * c2; a2.y += v2.y * c2; a2.z += v2.z * c2; a2.w += v2.w * c2;
        a3.x += v3.x * c3; a3.y += v3.y * c3; a3.z += v3.z * c3; a3.w += v3.w * c3;
    }
    for (; e < e1; ++e) {
        int s = csr_src[e];
        float c = dinv[s];
        float4 v = x4[(size_t)s * (D / 4) + q];
        a0.x += v.x * c; a0.y += v.y * c; a0.z += v.z * c; a0.w += v.w * c;
    }
    float4 acc;
    acc.x = (a0.x + a1.x) + (a2.x + a3.x);
    acc.y = (a0.y + a1.y) + (a2.y + a3.y);
    acc.z = (a0.z + a1.z) + (a2.z + a3.z);
    acc.w = (a0.w + a1.w) + (a2.w + a3.w);
    hacc[(size_t)r * (D / 4) + q] = acc;
}

__global__ __launch_bounds__(256) void k_scatter(const float4* __restrict__ x4,
                                                 const int* __restrict__ src,
                                                 const int* __restrict__ dst,
                                                 const float* __restrict__ dinv,
                                                 float* hacc, int E) {
    int idx = blockIdx.x * 256 + threadIdx.x;
    int e = idx >> 5;
    if (e >= E) return;
    int q = idx & 31;
    int s = src[e];
    int t = dst[e];
    float sc = dinv[s];
    float4 v = x4[(size_t)s * (D / 4) + q];
    float* h = hacc + (size_t)t * D + q * 4;
    unsafeAtomicAdd(h + 0, v.x * sc);
    unsafeAtomicAdd(h + 1, v.y * sc);
    unsafeAtomicAdd(h + 2, v.z * sc);
    unsafeAtomicAdd(h + 3, v.w * sc);
}

// ======================= fused epilogue (shared) =========================

__global__ __launch_bounds__(256) void k_final(float* io,
                                               const float* __restrict__ dinv,
                                               const float* __restrict__ h0,
                                               const float* __restrict__ x,
                                               const float* __restrict__ W,
                                               const float* __restrict__ lamda_p,
                                               const float* __restrict__ alpha_p,
                                               const void* __restrict__ l_p,
                                               int n) {
    __shared__ float sW[D * D];
    __shared__ float sSup[32][D];
    const int t = threadIdx.x;

    {
        const float4* W4 = (const float4*)W;
        float4* sW4 = (float4*)sW;
        #pragma unroll
        for (int i = 0; i < (D * D / 4) / 256; ++i)
            sW4[i * 256 + t] = W4[i * 256 + t];
    }

    const float alpha = *alpha_p;
    const float lamda = *lamda_p;
    const float lf = int_or_float(l_p);
    const float theta = logf(lamda / lf + 1.0f);
    const float omt = 1.0f - theta;
    const float oma = 1.0f - alpha;

    const int base = blockIdx.x * 32;

    {
        const float4* hacc4 = (const float4*)io;
        const float4* h04 = (const float4*)h0;
        #pragma unroll
        for (int i = 0; i < 4; ++i) {
            int v = i * 256 + t;
            int tr = v >> 5;
            int q = v & 31;
            int r = base + tr;
            float4 sup = make_float4(0.f, 0.f, 0.f, 0.f);
            if (r < n) {
                float ca = oma * dinv[r];
                float4 a = hacc4[(size_t)r * (D / 4) + q];
                float4 b = h04[(size_t)r * (D / 4) + q];
                sup.x = ca * a.x + alpha * b.x;
                sup.y = ca * a.y + alpha * b.y;
                sup.z = ca * a.z + alpha * b.z;
                sup.w = ca * a.w + alpha * b.w;
            }
            *(float4*)&sSup[tr][q * 4] = sup;
        }
    }
    __syncthreads();

    const int cg = t & 31;
    const int rb = t >> 5;
    float acc[4][4] = {};
    const float4* sW4 = (const float4*)sW;
    #pragma unroll 4
    for (int k = 0; k < D; ++k) {
        float4 w = sW4[k * 32 + cg];
        #pragma unroll
        for (int j = 0; j < 4; ++j) {
            float s = sSup[rb * 4 + j][k];
            acc[j][0] += s * w.x;
            acc[j][1] += s * w.y;
            acc[j][2] += s * w.z;
            acc[j][3] += s * w.w;
        }
    }

    #pragma unroll
    for (int j = 0; j < 4; ++j) {
        int tr = rb * 4 + j;
        int r = base + tr;
        if (r < n) {
            float4 xi = ((const float4*)x)[(size_t)r * (D / 4) + cg];
            float4 sp = *(const float4*)&sSup[tr][cg * 4];
            float4 o;
            o.x = theta * acc[j][0] + omt * sp.x + xi.x;
            o.y = theta * acc[j][1] + omt * sp.y + xi.y;
            o.z = theta * acc[j][2] + omt * sp.z + xi.z;
            o.w = theta * acc[j][3] + omt * sp.w + xi.w;
            ((float4*)io)[(size_t)r * (D / 4) + cg] = o;
        }
    }
}

// ================================ host ===================================

extern "C" void kernel_launch(void* const* d_in, const int* in_sizes, int n_in,
                              void* d_out, int out_size, void* d_ws, size_t ws_size,
                              hipStream_t stream) {
    const float* x = (const float*)d_in[0];
    const int* esrc = (const int*)d_in[1];
    const int* edst = (const int*)d_in[2];
    const float* h0 = (const float*)d_in[3];
    const float* W = (const float*)d_in[4];
    const float* lamda_p = (const float*)d_in[5];
    const float* alpha_p = (const float*)d_in[6];
    const void* l_p = d_in[7];

    const int E = in_sizes[1];
    const int n = in_sizes[0] / D;

    char* w = (char*)d_ws;

    // ---- tier-1 layout ----
    size_t o_deg = 0;                                            // n ints
    size_t o_cnt = ((size_t)n * 4 + 15) & ~15ull;                // 1 int (+pad)
    size_t o_dinv = o_cnt + 16;                                  // n floats
    size_t o_op  = (o_dinv + (size_t)n * 4 + 15) & ~15ull;       // OCAP int2
    size_t o_xs  = (o_op + (size_t)OCAP * 8 + 15) & ~15ull;      // n*128 bf16
    size_t o_pl  = (o_xs + (size_t)n * 256 + 15) & ~15ull;       // P_MAX*n ints
    size_t need1 = o_pl + (size_t)P_MAX * n * 4;

    if (ws_size >= need1) {
        int* deg = (int*)(w + o_deg);
        int* cnt = (int*)(w + o_cnt);
        float* dinv = (float*)(w + o_dinv);
        int2* opairs = (int2*)(w + o_op);
        uint4* xs4 = (uint4*)(w + o_xs);
        int* planes = (int*)(w + o_pl);

        hipMemsetAsync(w, 0, o_cnt + 16, stream);   // deg + cnt

        int chunks = (E + CHUNK - 1) / CHUNK;
        k_rank<<<chunks * 8, 256, 0, stream>>>(esrc, edst, deg, planes, cnt,
                                               opairs, E, n);
        k_scale<<<(n * 16 + 255) / 256, 256, 0, stream>>>(
            (const float4*)x, deg, xs4, dinv, n);
        k_gather2<<<(n * 16 + 255) / 256, 256, 0, stream>>>(
            xs4, planes, deg, (float4*)d_out, n);
        k_oflow<<<8, 256, 0, stream>>>(cnt, opairs, (const uint2*)(w + o_xs),
                                       (float*)d_out);
        k_final<<<(n + 31) / 32, 256, 0, stream>>>(
            (float*)d_out, dinv, h0, x, W, lamda_p, alpha_p, l_p, n);
        return;
    }

    // ---- tier-2: old CSR path ----
    const int nb = (n + 1023) / 1024;
    size_t t_deg = 0;
    size_t t_off = (t_deg + (size_t)n * 4 + 15) & ~15ull;
    size_t t_cur = (t_off + (size_t)(n + 1) * 4 + 15) & ~15ull;
    size_t t_bs  = (t_cur + (size_t)n * 4 + 15) & ~15ull;
    size_t t_bo  = (t_bs + (size_t)nb * 4 + 15) & ~15ull;
    size_t t_csr = (t_bo + (size_t)nb * 4 + 15) & ~15ull;
    size_t need2 = t_csr + (size_t)E * 4;

    int* deg = (int*)(w + t_deg);
    float* dinv = (float*)(w + t_deg);

    hipMemsetAsync(deg, 0, (size_t)n * sizeof(int), stream);
    k_deg<<<(E + 255) / 256, 256, 0, stream>>>(edst, deg, E);

    if (ws_size >= need2 && nb <= 1024) {
        int* offsets = (int*)(w + t_off);
        int* cursor  = (int*)(w + t_cur);
        int* bsum    = (int*)(w + t_bs);
        int* boff    = (int*)(w + t_bo);
        int* csr_src = (int*)(w + t_csr);

        k_scan1<<<nb, 256, 0, stream>>>(deg, bsum, n);
        k_scan2<<<1, 64, 0, stream>>>(bsum, boff, offsets, nb, n);
        k_scan3<<<nb, 256, 0, stream>>>(deg, boff, offsets, cursor, n);
        k_csr<<<(E + 255) / 256, 256, 0, stream>>>(esrc, edst, cursor, csr_src, E);
        k_gather<<<((size_t)n * 32 + 255) / 256, 256, 0, stream>>>(
            (const float4*)x, csr_src, offsets, dinv, (float4*)d_out, n);
    } else {
        k_dinv<<<(n + 255) / 256, 256, 0, stream>>>(deg, n);
        hipMemsetAsync(d_out, 0, (size_t)n * D * sizeof(float), stream);
        k_scatter<<<((size_t)E * 32 + 255) / 256, 256, 0, stream>>>(
            (const float4*)x, esrc, edst, dinv, (float*)d_out, E);
    }

    k_final<<<(n + 31) / 32, 256, 0, stream>>>(
        (float*)d_out, dinv, h0, x, W, lamda_p, alpha_p, l_p, n);
}

// Round 5
// 132.178 us; speedup vs baseline: 10.8198x; 1.0419x over previous
//
#include <hip/hip_runtime.h>
#include <math.h>

#define D 128
#define P_MAX 64        // plane capacity (max supported in-degree before overflow path)
#define OCAP 65536      // overflow edge capacity
#define CHUNK 2048      // edges per chunk in k_rank

using bf16x8 = __attribute__((ext_vector_type(8))) short;
using f32x4  = __attribute__((ext_vector_type(4))) float;

__device__ __forceinline__ float int_or_float(const void* p) {
    int iv = *(const int*)p;
    if (iv > -1000000 && iv < 1000000) return (float)iv;
    return __int_as_float(iv);
}

__device__ __forceinline__ unsigned bf16_rne(float f) {
    unsigned u = __float_as_uint(f);
    return (u + 0x7fffu + ((u >> 16) & 1u)) >> 16;
}
__device__ __forceinline__ unsigned pack_bf2(float a, float b) {
    return bf16_rne(a) | (bf16_rne(b) << 16);
}
__device__ __forceinline__ float bf16_to_f(unsigned short u) {
    return __uint_as_float(((unsigned)u) << 16);
}

// ============================ TIER-1 kernels =============================

// k_rank: deg count + plane-format CSR in one pass, XCD-sliced.
__global__ __launch_bounds__(256) void k_rank(const int* __restrict__ src,
                                              const int* __restrict__ dst,
                                              int* __restrict__ deg,
                                              int* __restrict__ planes,
                                              int* __restrict__ cnt,
                                              int2* __restrict__ opairs,
                                              int E, int n) {
    const int slice = blockIdx.x & 7;
    const int chunk = blockIdx.x >> 3;
    int base = chunk * CHUNK;
    int end = base + CHUNK;
    if (end > E) end = E;
    for (int i = base + threadIdx.x; i < end; i += 256) {
        int t = dst[i];
        if (((t >> 4) & 7) == slice) {
            int s = src[i];
            int rk = atomicAdd(&deg[t], 1);
            if (rk < P_MAX) {
                planes[rk * n + t] = s;
            } else {
                int o = atomicAdd(cnt, 1);
                if (o < OCAP) opairs[o] = make_int2(s, t);
            }
        }
    }
}

// k_scale: xs[r] = bf16(x[r] * dinv[r]); also writes dinv[r].
__global__ __launch_bounds__(256) void k_scale(const float4* __restrict__ x4,
                                               const int* __restrict__ deg,
                                               uint4* __restrict__ xs4,
                                               float* __restrict__ dinv, int n) {
    int gid = blockIdx.x * 256 + threadIdx.x;
    int r = gid >> 4;
    if (r >= n) return;
    int q = gid & 15;
    int d = deg[r];
    if (d < 1) d = 1;
    float di = rsqrtf((float)d);
    float4 v0 = x4[(size_t)r * 32 + q * 2];
    float4 v1 = x4[(size_t)r * 32 + q * 2 + 1];
    uint4 o;
    o.x = pack_bf2(v0.x * di, v0.y * di);
    o.y = pack_bf2(v0.z * di, v0.w * di);
    o.z = pack_bf2(v1.x * di, v1.y * di);
    o.w = pack_bf2(v1.z * di, v1.w * di);
    xs4[(size_t)r * 16 + q] = o;
    if (q == 0) dinv[r] = di;
}

__device__ __forceinline__ void acc8(float* a, uint4 v) {
    a[0] += __uint_as_float(v.x << 16);
    a[1] += __uint_as_float(v.x & 0xffff0000u);
    a[2] += __uint_as_float(v.y << 16);
    a[3] += __uint_as_float(v.y & 0xffff0000u);
    a[4] += __uint_as_float(v.z << 16);
    a[5] += __uint_as_float(v.z & 0xffff0000u);
    a[6] += __uint_as_float(v.w << 16);
    a[7] += __uint_as_float(v.w & 0xffff0000u);
}

// k_gather2: pull-gather over plane format.
__global__ __launch_bounds__(256) void k_gather2(const uint4* __restrict__ xs4,
                                                 const int* __restrict__ planes,
                                                 const int* __restrict__ deg,
                                                 float4* __restrict__ hacc, int n) {
    int gid = blockIdx.x * 256 + threadIdx.x;
    int r = gid >> 4;
    if (r >= n) return;
    int q = gid & 15;
    int d = deg[r];
    if (d > P_MAX) d = P_MAX;
    float a0[8] = {}, a1[8] = {}, a2[8] = {}, a3[8] = {};
    int p = 0;
    for (; p + 4 <= d; p += 4) {
        int s0 = planes[(p + 0) * n + r];
        int s1 = planes[(p + 1) * n + r];
        int s2 = planes[(p + 2) * n + r];
        int s3 = planes[(p + 3) * n + r];
        uint4 v0 = xs4[(size_t)s0 * 16 + q];
        uint4 v1 = xs4[(size_t)s1 * 16 + q];
        uint4 v2 = xs4[(size_t)s2 * 16 + q];
        uint4 v3 = xs4[(size_t)s3 * 16 + q];
        acc8(a0, v0);
        acc8(a1, v1);
        acc8(a2, v2);
        acc8(a3, v3);
    }
    for (; p < d; ++p) {
        int s = planes[p * n + r];
        uint4 v = xs4[(size_t)s * 16 + q];
        acc8(a0, v);
    }
    float4 o0, o1;
    o0.x = (a0[0] + a1[0]) + (a2[0] + a3[0]);
    o0.y = (a0[1] + a1[1]) + (a2[1] + a3[1]);
    o0.z = (a0[2] + a1[2]) + (a2[2] + a3[2]);
    o0.w = (a0[3] + a1[3]) + (a2[3] + a3[3]);
    o1.x = (a0[4] + a1[4]) + (a2[4] + a3[4]);
    o1.y = (a0[5] + a1[5]) + (a2[5] + a3[5]);
    o1.z = (a0[6] + a1[6]) + (a2[6] + a3[6]);
    o1.w = (a0[7] + a1[7]) + (a2[7] + a3[7]);
    hacc[(size_t)r * 32 + q * 2] = o0;
    hacc[(size_t)r * 32 + q * 2 + 1] = o1;
}

// k_oflow: add overflow edges (rank >= P_MAX) into hacc. Normally cnt == 0.
__global__ __launch_bounds__(256) void k_oflow(const int* __restrict__ cnt,
                                               const int2* __restrict__ opairs,
                                               const uint2* __restrict__ xs2,
                                               float* __restrict__ out) {
    int c = *cnt;
    if (c > OCAP) c = OCAP;
    int total = c * 32;
    for (int idx = blockIdx.x * 256 + threadIdx.x; idx < total;
         idx += gridDim.x * 256) {
        int e = idx >> 5, q = idx & 31;
        int2 pr = opairs[e];
        uint2 v = xs2[(size_t)pr.x * 32 + q];
        float* o = out + (size_t)pr.y * D + q * 4;
        unsafeAtomicAdd(o + 0, __uint_as_float(v.x << 16));
        unsafeAtomicAdd(o + 1, __uint_as_float(v.x & 0xffff0000u));
        unsafeAtomicAdd(o + 2, __uint_as_float(v.y << 16));
        unsafeAtomicAdd(o + 3, __uint_as_float(v.y & 0xffff0000u));
    }
}

// k_prepw: Wt[c][k] = bf16(W[k][c])  (128x128, 32 KB)
__global__ __launch_bounds__(256) void k_prepw(const float* __restrict__ W,
                                               unsigned short* __restrict__ wt) {
    int i = blockIdx.x * 256 + threadIdx.x;
    if (i < D * D) {
        int k = i >> 7, c = i & 127;
        wt[c * D + k] = (unsigned short)bf16_rne(W[i]);
    }
}

// k_final_mfma: support = (1-a)*dinv*hacc + a*h0 (bf16 in LDS, swizzled);
// out = theta*(support @ W) + (1-theta)*support + x  via mfma_f32_16x16x32_bf16.
// Block = 64 rows, 4 waves x 16 rows. LDS 48 KB -> 3 blocks/CU.
__global__ __launch_bounds__(256) void k_final_mfma(
        float* io, const float* __restrict__ dinv,
        const float* __restrict__ h0, const float* __restrict__ x,
        const unsigned short* __restrict__ wt,
        const float* __restrict__ lamda_p, const float* __restrict__ alpha_p,
        const void* __restrict__ l_p, int n) {
    __shared__ unsigned short sS[64 * D];    // 16 KB support bf16, swizzled
    __shared__ unsigned short sW[D * D];     // 32 KB Wt bf16, swizzled
    const int t = threadIdx.x;
    const int base = blockIdx.x * 64;

    const float alpha = *alpha_p;
    const float lamda = *lamda_p;
    const float lf = int_or_float(l_p);
    const float theta = logf(lamda / lf + 1.0f);
    const float omt = 1.0f - theta;
    const float oma = 1.0f - alpha;

    // stage Wt -> sW (16B chunks, XOR swizzle byte ^= ((row&7)<<4))
    {
        const uint4* wt4 = (const uint4*)wt;
        #pragma unroll
        for (int i = t; i < 2048; i += 256) {
            uint4 v = wt4[i];
            int c = i >> 4;                  // row (0..127), 16 chunks per row
            int boff = (i & 15) << 4;        // byte offset in row
            int sb = (c << 8) | (boff ^ ((c & 7) << 4));
            *(uint4*)((char*)sW + sb) = v;
        }
    }

    // stage support -> sS (8B chunks: float4 -> 4 bf16)
    {
        const float4* hacc4 = (const float4*)io;
        const float4* h04 = (const float4*)h0;
        #pragma unroll
        for (int i = t; i < 2048; i += 256) {
            int tr = i >> 5;                 // tile row 0..63
            int ch = i & 31;                 // float4 chunk in row
            int r = base + tr;
            uint2 o = make_uint2(0u, 0u);
            if (r < n) {
                float ca = oma * dinv[r];
                float4 a = hacc4[(size_t)r * 32 + ch];
                float4 b = h04[(size_t)r * 32 + ch];
                o.x = pack_bf2(ca * a.x + alpha * b.x, ca * a.y + alpha * b.y);
                o.y = pack_bf2(ca * a.z + alpha * b.z, ca * a.w + alpha * b.w);
            }
            int boff = ch << 3;              // byte offset in row
            int sb = (tr << 8) | (boff ^ ((tr & 7) << 4));
            *(uint2*)((char*)sS + sb) = o;
        }
    }
    __syncthreads();

    const int wid = t >> 6;
    const int lane = t & 63;
    const int lrow = lane & 15;     // A row / B col within 16-tile
    const int kg = lane >> 4;       // k-group 0..3 (8 contiguous k each)
    const int wrow = wid * 16;      // wave's row base within 64-row tile

    // A-fragments: afr[kb] = sS[wrow+lrow][kb*32 + kg*8 .. +8]
    bf16x8 afr[4];
    #pragma unroll
    for (int kb = 0; kb < 4; ++kb) {
        int rr = wrow + lrow;
        int boff = kb * 64 + kg * 16;
        int sb = (rr << 8) | (boff ^ ((rr & 7) << 4));
        afr[kb] = *(bf16x8*)((char*)sS + sb);
    }

    f32x4 acc[8];
    #pragma unroll
    for (int ct = 0; ct < 8; ++ct) {
        acc[ct] = (f32x4){0.f, 0.f, 0.f, 0.f};
        #pragma unroll
        for (int kb = 0; kb < 4; ++kb) {
            int c = ct * 16 + lrow;
            int boff = kb * 64 + kg * 16;
            int sb = (c << 8) | (boff ^ ((c & 7) << 4));
            bf16x8 bfr = *(bf16x8*)((char*)sW + sb);
            acc[ct] = __builtin_amdgcn_mfma_f32_16x16x32_bf16(afr[kb], bfr,
                                                              acc[ct], 0, 0, 0);
        }
    }

    // epilogue: D[row = wrow + kg*4 + reg][col = ct*16 + lrow]
    #pragma unroll
    for (int ct = 0; ct < 8; ++ct) {
        #pragma unroll
        for (int reg = 0; reg < 4; ++reg) {
            int tr = wrow + kg * 4 + reg;
            int r = base + tr;
            if (r < n) {
                int c = ct * 16 + lrow;
                int sb = (tr << 8) | ((c * 2) ^ ((tr & 7) << 4));
                float sup = bf16_to_f(*(const unsigned short*)((char*)sS + sb));
                float xi = x[(size_t)r * D + c];
                io[(size_t)r * D + c] = theta * acc[ct][reg] + omt * sup + xi;
            }
        }
    }
}

// ==================== TIER-2 (old CSR path) kernels ======================

__global__ __launch_bounds__(256) void k_deg(const int* __restrict__ dst,
                                             int* __restrict__ deg, int E) {
    int i = blockIdx.x * 256 + threadIdx.x;
    if (i < E) atomicAdd(&deg[dst[i]], 1);
}

__global__ __launch_bounds__(256) void k_dinv(int* dd, int n) {
    int i = blockIdx.x * 256 + threadIdx.x;
    if (i < n) {
        int d = dd[i];
        if (d < 1) d = 1;
        ((float*)dd)[i] = rsqrtf((float)d);
    }
}

__global__ __launch_bounds__(256) void k_scan1(const int* __restrict__ deg,
                                               int* __restrict__ bsum, int n) {
    __shared__ int red[256];
    int b = blockIdx.x, t = threadIdx.x;
    int base = b * 1024;
    int s = 0;
    #pragma unroll
    for (int i = 0; i < 4; ++i) {
        int idx = base + i * 256 + t;
        if (idx < n) s += deg[idx];
    }
    red[t] = s;
    __syncthreads();
    for (int k = 128; k > 0; k >>= 1) {
        if (t < k) red[t] += red[t + k];
        __syncthreads();
    }
    if (t == 0) bsum[b] = red[0];
}

__global__ void k_scan2(const int* __restrict__ bsum, int* __restrict__ boff,
                        int* __restrict__ offsets, int nb, int n) {
    if (threadIdx.x == 0) {
        int acc = 0;
        for (int i = 0; i < nb; ++i) { boff[i] = acc; acc += bsum[i]; }
        offsets[n] = acc;
    }
}

__global__ __launch_bounds__(256) void k_scan3(int* __restrict__ deg,
                                               const int* __restrict__ boff,
                                               int* __restrict__ offsets,
                                               int* __restrict__ cursor, int n) {
    __shared__ int ls[256];
    int b = blockIdx.x, t = threadIdx.x;
    int base = b * 1024 + t * 4;
    int v[4];
    #pragma unroll
    for (int i = 0; i < 4; ++i) v[i] = (base + i < n) ? deg[base + i] : 0;
    int mysum = v[0] + v[1] + v[2] + v[3];
    ls[t] = mysum;
    __syncthreads();
    for (int k = 1; k < 256; k <<= 1) {
        int add = (t >= k) ? ls[t - k] : 0;
        __syncthreads();
        ls[t] += add;
        __syncthreads();
    }
    int p = boff[b] + ls[t] - mysum;
    #pragma unroll
    for (int i = 0; i < 4; ++i) {
        if (base + i < n) {
            offsets[base + i] = p;
            cursor[base + i] = p;
            int d = v[i] < 1 ? 1 : v[i];
            ((float*)deg)[base + i] = rsqrtf((float)d);
        }
        p += v[i];
    }
}

__global__ __launch_bounds__(256) void k_csr(const int* __restrict__ src,
                                             const int* __restrict__ dst,
                                             int* __restrict__ cursor,
                                             int* __restrict__ csr_src, int E) {
    int i = blockIdx.x * 256 + threadIdx.x;
    if (i < E) {
        int pos = atomicAdd(&cursor[dst[i]], 1);
        csr_src[pos] = src[i];
    }
}

__global__ __launch_bounds__(256) void k_gather(const float4* __restrict__ x4,
                                                const int* __restrict__ csr_src,
                                                const int* __restrict__ offsets,
                                                const float* __restrict__ dinv,
                                                float4* __restrict__ hacc, int n) {
    int idx = blockIdx.x * 256 + threadIdx.x;
    int r = idx >> 5;
    if (r >= n) return;
    int q = idx & 31;
    int e0 = offsets[r], e1 = offsets[r + 1];
    float4 a0 = make_float4(0.f, 0.f, 0.f, 0.f);
    float4 a1 = make_float4(0.f, 0.f, 0.f, 0.f);
    float4 a2 = make_float4(0.f, 0.f, 0.f, 0.f);
    float4 a3 = make_float4(0.f, 0.f, 0.f, 0.f);
    int e = e0;
    for (; e + 4 <= e1; e += 4) {
        int s0 = csr_src[e + 0];
        int s1 = csr_src[e + 1];
        int s2 = csr_src[e + 2];
        int s3 = csr_src[e + 3];
        float c0 = dinv[s0], c1 = dinv[s1], c2 = dinv[s2], c3 = dinv[s3];
        float4 v0 = x4[(size_t)s0 * (D / 4) + q];
        float4 v1 = x4[(size_t)s1 * (D / 4) + q];
        float4 v2 = x4[(size_t)s2 * (D / 4) + q];
        float4 v3 = x4[(size_t)s3 * (D / 4) + q];
        a0.x += v0.x * c0; a0.y += v0.y * c0; a0.z += v0.z * c0; a0.w += v0.w * c0;
        a1.x += v1.x * c1; a1.y += v1.y * c1; a1.z += v1.z * c1; a1.w += v1.w * c1;
        a2.x += v2.x * c2; a2.y += v2.y * c2; a2.z += v2.z * c2; a2.w += v2.w * c2;
        a3.x += v3.x * c3; a3.y += v3.y * c3; a3.z += v3.z * c3; a3.w += v3.w * c3;
    }
    for (; e < e1; ++e) {
        int s = csr_src[e];
        float c = dinv[s];
        float4 v = x4[(size_t)s * (D / 4) + q];
        a0.x += v.x * c; a0.y += v.y * c; a0.z += v.z * c; a0.w += v.w * c;
    }
    float4 acc;
    acc.x = (a0.x + a1.x) + (a2.x + a3.x);
    acc.y = (a0.y + a1.y) + (a2.y + a3.y);
    acc.z = (a0.z + a1.z) + (a2.z + a3.z);
    acc.w = (a0.w + a1.w) + (a2.w + a3.w);
    hacc[(size_t)r * (D / 4) + q] = acc;
}

__global__ __launch_bounds__(256) void k_scatter(const float4* __restrict__ x4,
                                                 const int* __restrict__ src,
                                                 const int* __restrict__ dst,
                                                 const float* __restrict__ dinv,
                                                 float* hacc, int E) {
    int idx = blockIdx.x * 256 + threadIdx.x;
    int e = idx >> 5;
    if (e >= E) return;
    int q = idx & 31;
    int s = src[e];
    int t = dst[e];
    float sc = dinv[s];
    float4 v = x4[(size_t)s * (D / 4) + q];
    float* h = hacc + (size_t)t * D + q * 4;
    unsafeAtomicAdd(h + 0, v.x * sc);
    unsafeAtomicAdd(h + 1, v.y * sc);
    unsafeAtomicAdd(h + 2, v.z * sc);
    unsafeAtomicAdd(h + 3, v.w * sc);
}

// old VALU epilogue (fallback paths)
__global__ __launch_bounds__(256) void k_final(float* io,
                                               const float* __restrict__ dinv,
                                               const float* __restrict__ h0,
                                               const float* __restrict__ x,
                                               const float* __restrict__ W,
                                               const float* __restrict__ lamda_p,
                                               const float* __restrict__ alpha_p,
                                               const void* __restrict__ l_p,
                                               int n) {
    __shared__ float sW[D * D];
    __shared__ float sSup[32][D];
    const int t = threadIdx.x;

    {
        const float4* W4 = (const float4*)W;
        float4* sW4 = (float4*)sW;
        #pragma unroll
        for (int i = 0; i < (D * D / 4) / 256; ++i)
            sW4[i * 256 + t] = W4[i * 256 + t];
    }

    const float alpha = *alpha_p;
    const float lamda = *lamda_p;
    const float lf = int_or_float(l_p);
    const float theta = logf(lamda / lf + 1.0f);
    const float omt = 1.0f - theta;
    const float oma = 1.0f - alpha;

    const int base = blockIdx.x * 32;

    {
        const float4* hacc4 = (const float4*)io;
        const float4* h04 = (const float4*)h0;
        #pragma unroll
        for (int i = 0; i < 4; ++i) {
            int v = i * 256 + t;
            int tr = v >> 5;
            int q = v & 31;
            int r = base + tr;
            float4 sup = make_float4(0.f, 0.f, 0.f, 0.f);
            if (r < n) {
                float ca = oma * dinv[r];
                float4 a = hacc4[(size_t)r * (D / 4) + q];
                float4 b = h04[(size_t)r * (D / 4) + q];
                sup.x = ca * a.x + alpha * b.x;
                sup.y = ca * a.y + alpha * b.y;
                sup.z = ca * a.z + alpha * b.z;
                sup.w = ca * a.w + alpha * b.w;
            }
            *(float4*)&sSup[tr][q * 4] = sup;
        }
    }
    __syncthreads();

    const int cg = t & 31;
    const int rb = t >> 5;
    float acc[4][4] = {};
    const float4* sW4 = (const float4*)sW;
    #pragma unroll 4
    for (int k = 0; k < D; ++k) {
        float4 w = sW4[k * 32 + cg];
        #pragma unroll
        for (int j = 0; j < 4; ++j) {
            float s = sSup[rb * 4 + j][k];
            acc[j][0] += s * w.x;
            acc[j][1] += s * w.y;
            acc[j][2] += s * w.z;
            acc[j][3] += s * w.w;
        }
    }

    #pragma unroll
    for (int j = 0; j < 4; ++j) {
        int tr = rb * 4 + j;
        int r = base + tr;
        if (r < n) {
            float4 xi = ((const float4*)x)[(size_t)r * (D / 4) + cg];
            float4 sp = *(const float4*)&sSup[tr][cg * 4];
            float4 o;
            o.x = theta * acc[j][0] + omt * sp.x + xi.x;
            o.y = theta * acc[j][1] + omt * sp.y + xi.y;
            o.z = theta * acc[j][2] + omt * sp.z + xi.z;
            o.w = theta * acc[j][3] + omt * sp.w + xi.w;
            ((float4*)io)[(size_t)r * (D / 4) + cg] = o;
        }
    }
}

// ================================ host ===================================

extern "C" void kernel_launch(void* const* d_in, const int* in_sizes, int n_in,
                              void* d_out, int out_size, void* d_ws, size_t ws_size,
                              hipStream_t stream) {
    const float* x = (const float*)d_in[0];
    const int* esrc = (const int*)d_in[1];
    const int* edst = (const int*)d_in[2];
    const float* h0 = (const float*)d_in[3];
    const float* W = (const float*)d_in[4];
    const float* lamda_p = (const float*)d_in[5];
    const float* alpha_p = (const float*)d_in[6];
    const void* l_p = d_in[7];

    const int E = in_sizes[1];
    const int n = in_sizes[0] / D;

    char* w = (char*)d_ws;

    // ---- tier-1 layout ----
    size_t o_deg = 0;                                            // n ints
    size_t o_cnt = ((size_t)n * 4 + 15) & ~15ull;                // 1 int (+pad)
    size_t o_dinv = o_cnt + 16;                                  // n floats
    size_t o_op  = (o_dinv + (size_t)n * 4 + 15) & ~15ull;       // OCAP int2
    size_t o_xs  = (o_op + (size_t)OCAP * 8 + 15) & ~15ull;      // n*128 bf16
    size_t o_wt  = (o_xs + (size_t)n * 256 + 15) & ~15ull;       // 128*128 bf16
    size_t o_pl  = (o_wt + (size_t)D * D * 2 + 15) & ~15ull;     // P_MAX*n ints
    size_t need1 = o_pl + (size_t)P_MAX * n * 4;

    if (ws_size >= need1) {
        int* deg = (int*)(w + o_deg);
        int* cnt = (int*)(w + o_cnt);
        float* dinv = (float*)(w + o_dinv);
        int2* opairs = (int2*)(w + o_op);
        uint4* xs4 = (uint4*)(w + o_xs);
        unsigned short* wt = (unsigned short*)(w + o_wt);
        int* planes = (int*)(w + o_pl);

        hipMemsetAsync(w, 0, o_cnt + 16, stream);   // deg + cnt

        int chunks = (E + CHUNK - 1) / CHUNK;
        k_prepw<<<(D * D + 255) / 256, 256, 0, stream>>>(W, wt);
        k_rank<<<chunks * 8, 256, 0, stream>>>(esrc, edst, deg, planes, cnt,
                                               opairs, E, n);
        k_scale<<<(n * 16 + 255) / 256, 256, 0, stream>>>(
            (const float4*)x, deg, xs4, dinv, n);
        k_gather2<<<(n * 16 + 255) / 256, 256, 0, stream>>>(
            xs4, planes, deg, (float4*)d_out, n);
        k_oflow<<<8, 256, 0, stream>>>(cnt, opairs, (const uint2*)(w + o_xs),
                                       (float*)d_out);
        k_final_mfma<<<(n + 63) / 64, 256, 0, stream>>>(
            (float*)d_out, dinv, h0, x, wt, lamda_p, alpha_p, l_p, n);
        return;
    }

    // ---- tier-2: old CSR path ----
    const int nb = (n + 1023) / 1024;
    size_t t_deg = 0;
    size_t t_off = (t_deg + (size_t)n * 4 + 15) & ~15ull;
    size_t t_cur = (t_off + (size_t)(n + 1) * 4 + 15) & ~15ull;
    size_t t_bs  = (t_cur + (size_t)n * 4 + 15) & ~15ull;
    size_t t_bo  = (t_bs + (size_t)nb * 4 + 15) & ~15ull;
    size_t t_csr = (t_bo + (size_t)nb * 4 + 15) & ~15ull;
    size_t need2 = t_csr + (size_t)E * 4;

    int* deg = (int*)(w + t_deg);
    float* dinv = (float*)(w + t_deg);

    hipMemsetAsync(deg, 0, (size_t)n * sizeof(int), stream);
    k_deg<<<(E + 255) / 256, 256, 0, stream>>>(edst, deg, E);

    if (ws_size >= need2 && nb <= 1024) {
        int* offsets = (int*)(w + t_off);
        int* cursor  = (int*)(w + t_cur);
        int* bsum    = (int*)(w + t_bs);
        int* boff    = (int*)(w + t_bo);
        int* csr_src = (int*)(w + t_csr);

        k_scan1<<<nb, 256, 0, stream>>>(deg, bsum, n);
        k_scan2<<<1, 64, 0, stream>>>(bsum, boff, offsets, nb, n);
        k_scan3<<<nb, 256, 0, stream>>>(deg, boff, offsets, cursor, n);
        k_csr<<<(E + 255) / 256, 256, 0, stream>>>(esrc, edst, cursor, csr_src, E);
        k_gather<<<((size_t)n * 32 + 255) / 256, 256, 0, stream>>>(
            (const float4*)x, csr_src, offsets, dinv, (float4*)d_out, n);
    } else {
        k_dinv<<<(n + 255) / 256, 256, 0, stream>>>(deg, n);
        hipMemsetAsync(d_out, 0, (size_t)n * D * sizeof(float), stream);
        k_scatter<<<((size_t)E * 32 + 255) / 256, 256, 0, stream>>>(
            (const float4*)x, esrc, edst, dinv, (float*)d_out, E);
    }

    k_final<<<(n + 31) / 32, 256, 0, stream>>>(
        (float*)d_out, dinv, h0, x, W, lamda_p, alpha_p, l_p, n);
}

// Round 6
// 116.353 us; speedup vs baseline: 12.2915x; 1.1360x over previous
//
#include <hip/hip_runtime.h>
#include <math.h>

#define D 128
#define P_MAX 64        // plane capacity (max in-degree before overflow path)
#define OCAP 65536      // overflow edge capacity
#define CHUNK 2048      // edges per chunk in k_rank

using bf16x8 = __attribute__((ext_vector_type(8))) short;
using f32x4  = __attribute__((ext_vector_type(4))) float;

__device__ __forceinline__ float int_or_float(const void* p) {
    int iv = *(const int*)p;
    if (iv > -1000000 && iv < 1000000) return (float)iv;
    return __int_as_float(iv);
}

__device__ __forceinline__ unsigned bf16_rne(float f) {
    unsigned u = __float_as_uint(f);
    return (u + 0x7fffu + ((u >> 16) & 1u)) >> 16;
}
__device__ __forceinline__ unsigned pack_bf2(float a, float b) {
    return bf16_rne(a) | (bf16_rne(b) << 16);
}

// ============================ TIER-1 kernels =============================

// k_rank: deg count + plane-format CSR in one pass, XCD-sliced.
__global__ __launch_bounds__(256) void k_rank(const int* __restrict__ src,
                                              const int* __restrict__ dst,
                                              int* __restrict__ deg,
                                              int* __restrict__ planes,
                                              int* __restrict__ cnt,
                                              int2* __restrict__ opairs,
                                              int E, int n) {
    const int slice = blockIdx.x & 7;
    const int chunk = blockIdx.x >> 3;
    int base = chunk * CHUNK;
    int end = base + CHUNK;
    if (end > E) end = E;
    for (int i = base + threadIdx.x; i < end; i += 256) {
        int t = dst[i];
        if (((t >> 4) & 7) == slice) {
            int s = src[i];
            int rk = atomicAdd(&deg[t], 1);
            if (rk < P_MAX) {
                planes[rk * n + t] = s;
            } else {
                int o = atomicAdd(cnt, 1);
                if (o < OCAP) opairs[o] = make_int2(s, t);
            }
        }
    }
}

// k_scale: xs[r] = bf16(x[r] * dinv[r]). 16 threads/row, 8 elems each.
__global__ __launch_bounds__(256) void k_scale(const float4* __restrict__ x4,
                                               const int* __restrict__ deg,
                                               uint4* __restrict__ xs4, int n) {
    int gid = blockIdx.x * 256 + threadIdx.x;
    int r = gid >> 4;
    if (r >= n) return;
    int q = gid & 15;
    int d = deg[r];
    if (d < 1) d = 1;
    float di = rsqrtf((float)d);
    float4 v0 = x4[(size_t)r * 32 + q * 2];
    float4 v1 = x4[(size_t)r * 32 + q * 2 + 1];
    uint4 o;
    o.x = pack_bf2(v0.x * di, v0.y * di);
    o.y = pack_bf2(v0.z * di, v0.w * di);
    o.z = pack_bf2(v1.x * di, v1.y * di);
    o.w = pack_bf2(v1.z * di, v1.w * di);
    xs4[(size_t)r * 16 + q] = o;
}

__device__ __forceinline__ void acc8(float* a, uint4 v) {
    a[0] += __uint_as_float(v.x << 16);
    a[1] += __uint_as_float(v.x & 0xffff0000u);
    a[2] += __uint_as_float(v.y << 16);
    a[3] += __uint_as_float(v.y & 0xffff0000u);
    a[4] += __uint_as_float(v.z << 16);
    a[5] += __uint_as_float(v.z & 0xffff0000u);
    a[6] += __uint_as_float(v.w << 16);
    a[7] += __uint_as_float(v.w & 0xffff0000u);
}

// k_prepw2: Wm = theta*W + (1-theta)*I, bf16, laid out in MFMA B-fragment
// order: entry16B[ct*256 + kb*64 + kg*16 + lc] = Wm^T[ct*16+lc][kb*32+kg*8 ..+8]
__global__ __launch_bounds__(256) void k_prepw2(const float* __restrict__ W,
                                                uint4* __restrict__ wmt,
                                                const float* __restrict__ lamda_p,
                                                const void* __restrict__ l_p) {
    int tid = blockIdx.x * 256 + threadIdx.x;
    if (tid >= 2048) return;
    float lamda = *lamda_p;
    float lf = int_or_float(l_p);
    float theta = logf(lamda / lf + 1.0f);
    float omt = 1.0f - theta;
    int ct = tid >> 8, kb = (tid >> 6) & 3, kg = (tid >> 4) & 3, lc = tid & 15;
    int c = ct * 16 + lc;
    int k0 = kb * 32 + kg * 8;
    float v[8];
    #pragma unroll
    for (int j = 0; j < 8; ++j) {
        float wv = theta * W[(size_t)(k0 + j) * D + c];
        if (k0 + j == c) wv += omt;
        v[j] = wv;
    }
    uint4 o;
    o.x = pack_bf2(v[0], v[1]);
    o.y = pack_bf2(v[2], v[3]);
    o.z = pack_bf2(v[4], v[5]);
    o.w = pack_bf2(v[6], v[7]);
    wmt[tid] = o;
}

// k_gather3: pull-gather + support fusion. Writes support row r (bf16, in
// A-fragment-internal order = plain linear k order) into the FIRST 256 B of
// out-row r (d_out dual-use; k_gemm reads it back and overwrites the row).
__global__ __launch_bounds__(256) void k_gather3(const uint4* __restrict__ xs4,
                                                 const int* __restrict__ planes,
                                                 const int* __restrict__ deg,
                                                 const int* __restrict__ cnt,
                                                 const int2* __restrict__ opairs,
                                                 const float* __restrict__ h0,
                                                 const float* __restrict__ alpha_p,
                                                 uint4* __restrict__ io, int n) {
    int gid = blockIdx.x * 256 + threadIdx.x;
    int r = gid >> 4;
    if (r >= n) return;
    int q = gid & 15;
    int d = deg[r];
    int dc = d < P_MAX ? d : P_MAX;
    float a0[8] = {}, a1[8] = {}, a2[8] = {}, a3[8] = {};
    int p = 0;
    for (; p + 4 <= dc; p += 4) {
        int s0 = planes[(p + 0) * n + r];
        int s1 = planes[(p + 1) * n + r];
        int s2 = planes[(p + 2) * n + r];
        int s3 = planes[(p + 3) * n + r];
        uint4 v0 = xs4[(size_t)s0 * 16 + q];
        uint4 v1 = xs4[(size_t)s1 * 16 + q];
        uint4 v2 = xs4[(size_t)s2 * 16 + q];
        uint4 v3 = xs4[(size_t)s3 * 16 + q];
        acc8(a0, v0);
        acc8(a1, v1);
        acc8(a2, v2);
        acc8(a3, v3);
    }
    for (; p < dc; ++p) {
        int s = planes[p * n + r];
        uint4 v = xs4[(size_t)s * 16 + q];
        acc8(a0, v);
    }
    if (d > P_MAX) {                    // never taken in practice (cnt == 0)
        int c = *cnt;
        if (c > OCAP) c = OCAP;
        for (int i = 0; i < c; ++i) {
            int2 pr = opairs[i];
            if (pr.y == r) {
                uint4 v = xs4[(size_t)pr.x * 16 + q];
                acc8(a0, v);
            }
        }
    }
    float di = rsqrtf((float)(d < 1 ? 1 : d));
    float alpha = *alpha_p;
    float ca = (1.0f - alpha) * di;
    const float4* h04 = (const float4*)h0;
    float4 hb0 = h04[(size_t)r * 32 + q * 2];
    float4 hb1 = h04[(size_t)r * 32 + q * 2 + 1];
    float s0 = ca * ((a0[0] + a1[0]) + (a2[0] + a3[0])) + alpha * hb0.x;
    float s1 = ca * ((a0[1] + a1[1]) + (a2[1] + a3[1])) + alpha * hb0.y;
    float s2 = ca * ((a0[2] + a1[2]) + (a2[2] + a3[2])) + alpha * hb0.z;
    float s3 = ca * ((a0[3] + a1[3]) + (a2[3] + a3[3])) + alpha * hb0.w;
    float s4 = ca * ((a0[4] + a1[4]) + (a2[4] + a3[4])) + alpha * hb1.x;
    float s5 = ca * ((a0[5] + a1[5]) + (a2[5] + a3[5])) + alpha * hb1.y;
    float s6 = ca * ((a0[6] + a1[6]) + (a2[6] + a3[6])) + alpha * hb1.z;
    float s7 = ca * ((a0[7] + a1[7]) + (a2[7] + a3[7])) + alpha * hb1.w;
    uint4 o;
    o.x = pack_bf2(s0, s1);
    o.y = pack_bf2(s2, s3);
    o.z = pack_bf2(s4, s5);
    o.w = pack_bf2(s6, s7);
    io[(size_t)r * 32 + q] = o;         // first 256 B of out-row r
}

// k_gemm: out = support @ Wm + x. No LDS, no barriers. 4 waves/block, one
// 16-row tile per wave. A-frags read from the wave's own out rows (written
// by k_gather3), then those rows are overwritten with the final result.
__global__ __launch_bounds__(256) void k_gemm(float* __restrict__ io,
                                              const float* __restrict__ x,
                                              const uint4* __restrict__ wmt,
                                              int n) {
    int wid = threadIdx.x >> 6;
    int lane = threadIdx.x & 63;
    int rt = blockIdx.x * 4 + wid;
    int ntiles = (n + 15) >> 4;
    if (rt >= ntiles) return;
    int lr = lane & 15;
    int kg = lane >> 4;

    // A-fragments: row rt*16+lr, k-slice kg*8 within each 32-k block
    bf16x8 a[4];
    int arow = rt * 16 + lr;
    if (arow >= n) arow = n - 1;
    const char* rowp = (const char*)io + (size_t)arow * 512;
    #pragma unroll
    for (int kb = 0; kb < 4; ++kb)
        a[kb] = *(const bf16x8*)(rowp + kb * 64 + kg * 16);

    const bf16x8* wfr = (const bf16x8*)wmt;
    #pragma unroll
    for (int ct = 0; ct < 8; ++ct) {
        f32x4 acc = (f32x4){0.f, 0.f, 0.f, 0.f};
        #pragma unroll
        for (int kb = 0; kb < 4; ++kb) {
            bf16x8 b = wfr[ct * 256 + kb * 64 + lane];
            acc = __builtin_amdgcn_mfma_f32_16x16x32_bf16(a[kb], b, acc, 0, 0, 0);
        }
        int c = ct * 16 + lr;
        #pragma unroll
        for (int reg = 0; reg < 4; ++reg) {
            int rr = rt * 16 + kg * 4 + reg;
            if (rr < n) {
                size_t off = (size_t)rr * D + c;
                io[off] = acc[reg] + x[off];
            }
        }
    }
}

// ==================== TIER-2 (old CSR path) kernels ======================

__global__ __launch_bounds__(256) void k_deg(const int* __restrict__ dst,
                                             int* __restrict__ deg, int E) {
    int i = blockIdx.x * 256 + threadIdx.x;
    if (i < E) atomicAdd(&deg[dst[i]], 1);
}

__global__ __launch_bounds__(256) void k_dinv(int* dd, int n) {
    int i = blockIdx.x * 256 + threadIdx.x;
    if (i < n) {
        int d = dd[i];
        if (d < 1) d = 1;
        ((float*)dd)[i] = rsqrtf((float)d);
    }
}

__global__ __launch_bounds__(256) void k_scan1(const int* __restrict__ deg,
                                               int* __restrict__ bsum, int n) {
    __shared__ int red[256];
    int b = blockIdx.x, t = threadIdx.x;
    int base = b * 1024;
    int s = 0;
    #pragma unroll
    for (int i = 0; i < 4; ++i) {
        int idx = base + i * 256 + t;
        if (idx < n) s += deg[idx];
    }
    red[t] = s;
    __syncthreads();
    for (int k = 128; k > 0; k >>= 1) {
        if (t < k) red[t] += red[t + k];
        __syncthreads();
    }
    if (t == 0) bsum[b] = red[0];
}

__global__ void k_scan2(const int* __restrict__ bsum, int* __restrict__ boff,
                        int* __restrict__ offsets, int nb, int n) {
    if (threadIdx.x == 0) {
        int acc = 0;
        for (int i = 0; i < nb; ++i) { boff[i] = acc; acc += bsum[i]; }
        offsets[n] = acc;
    }
}

__global__ __launch_bounds__(256) void k_scan3(int* __restrict__ deg,
                                               const int* __restrict__ boff,
                                               int* __restrict__ offsets,
                                               int* __restrict__ cursor, int n) {
    __shared__ int ls[256];
    int b = blockIdx.x, t = threadIdx.x;
    int base = b * 1024 + t * 4;
    int v[4];
    #pragma unroll
    for (int i = 0; i < 4; ++i) v[i] = (base + i < n) ? deg[base + i] : 0;
    int mysum = v[0] + v[1] + v[2] + v[3];
    ls[t] = mysum;
    __syncthreads();
    for (int k = 1; k < 256; k <<= 1) {
        int add = (t >= k) ? ls[t - k] : 0;
        __syncthreads();
        ls[t] += add;
        __syncthreads();
    }
    int p = boff[b] + ls[t] - mysum;
    #pragma unroll
    for (int i = 0; i < 4; ++i) {
        if (base + i < n) {
            offsets[base + i] = p;
            cursor[base + i] = p;
            int d = v[i] < 1 ? 1 : v[i];
            ((float*)deg)[base + i] = rsqrtf((float)d);
        }
        p += v[i];
    }
}

__global__ __launch_bounds__(256) void k_csr(const int* __restrict__ src,
                                             const int* __restrict__ dst,
                                             int* __restrict__ cursor,
                                             int* __restrict__ csr_src, int E) {
    int i = blockIdx.x * 256 + threadIdx.x;
    if (i < E) {
        int pos = atomicAdd(&cursor[dst[i]], 1);
        csr_src[pos] = src[i];
    }
}

__global__ __launch_bounds__(256) void k_gather(const float4* __restrict__ x4,
                                                const int* __restrict__ csr_src,
                                                const int* __restrict__ offsets,
                                                const float* __restrict__ dinv,
                                                float4* __restrict__ hacc, int n) {
    int idx = blockIdx.x * 256 + threadIdx.x;
    int r = idx >> 5;
    if (r >= n) return;
    int q = idx & 31;
    int e0 = offsets[r], e1 = offsets[r + 1];
    float4 a0 = make_float4(0.f, 0.f, 0.f, 0.f);
    float4 a1 = make_float4(0.f, 0.f, 0.f, 0.f);
    float4 a2 = make_float4(0.f, 0.f, 0.f, 0.f);
    float4 a3 = make_float4(0.f, 0.f, 0.f, 0.f);
    int e = e0;
    for (; e + 4 <= e1; e += 4) {
        int s0 = csr_src[e + 0];
        int s1 = csr_src[e + 1];
        int s2 = csr_src[e + 2];
        int s3 = csr_src[e + 3];
        float c0 = dinv[s0], c1 = dinv[s1], c2 = dinv[s2], c3 = dinv[s3];
        float4 v0 = x4[(size_t)s0 * (D / 4) + q];
        float4 v1 = x4[(size_t)s1 * (D / 4) + q];
        float4 v2 = x4[(size_t)s2 * (D / 4) + q];
        float4 v3 = x4[(size_t)s3 * (D / 4) + q];
        a0.x += v0.x * c0; a0.y += v0.y * c0; a0.z += v0.z * c0; a0.w += v0.w * c0;
        a1.x += v1.x * c1; a1.y += v1.y * c1; a1.z += v1.z * c1; a1.w += v1.w * c1;
        a2.x += v2.x * c2; a2.y += v2.y * c2; a2.z += v2.z * c2; a2.w += v2.w * c2;
        a3.x += v3.x * c3; a3.y += v3.y * c3; a3.z += v3.z * c3; a3.w += v3.w * c3;
    }
    for (; e < e1; ++e) {
        int s = csr_src[e];
        float c = dinv[s];
        float4 v = x4[(size_t)s * (D / 4) + q];
        a0.x += v.x * c; a0.y += v.y * c; a0.z += v.z * c; a0.w += v.w * c;
    }
    float4 acc;
    acc.x = (a0.x + a1.x) + (a2.x + a3.x);
    acc.y = (a0.y + a1.y) + (a2.y + a3.y);
    acc.z = (a0.z + a1.z) + (a2.z + a3.z);
    acc.w = (a0.w + a1.w) + (a2.w + a3.w);
    hacc[(size_t)r * (D / 4) + q] = acc;
}

__global__ __launch_bounds__(256) void k_scatter(const float4* __restrict__ x4,
                                                 const int* __restrict__ src,
                                                 const int* __restrict__ dst,
                                                 const float* __restrict__ dinv,
                                                 float* hacc, int E) {
    int idx = blockIdx.x * 256 + threadIdx.x;
    int e = idx >> 5;
    if (e >= E) return;
    int q = idx & 31;
    int s = src[e];
    int t = dst[e];
    float sc = dinv[s];
    float4 v = x4[(size_t)s * (D / 4) + q];
    float* h = hacc + (size_t)t * D + q * 4;
    unsafeAtomicAdd(h + 0, v.x * sc);
    unsafeAtomicAdd(h + 1, v.y * sc);
    unsafeAtomicAdd(h + 2, v.z * sc);
    unsafeAtomicAdd(h + 3, v.w * sc);
}

// old VALU epilogue (fallback paths)
__global__ __launch_bounds__(256) void k_final(float* io,
                                               const float* __restrict__ dinv,
                                               const float* __restrict__ h0,
                                               const float* __restrict__ x,
                                               const float* __restrict__ W,
                                               const float* __restrict__ lamda_p,
                                               const float* __restrict__ alpha_p,
                                               const void* __restrict__ l_p,
                                               int n) {
    __shared__ float sW[D * D];
    __shared__ float sSup[32][D];
    const int t = threadIdx.x;

    {
        const float4* W4 = (const float4*)W;
        float4* sW4 = (float4*)sW;
        #pragma unroll
        for (int i = 0; i < (D * D / 4) / 256; ++i)
            sW4[i * 256 + t] = W4[i * 256 + t];
    }

    const float alpha = *alpha_p;
    const float lamda = *lamda_p;
    const float lf = int_or_float(l_p);
    const float theta = logf(lamda / lf + 1.0f);
    const float omt = 1.0f - theta;
    const float oma = 1.0f - alpha;

    const int base = blockIdx.x * 32;

    {
        const float4* hacc4 = (const float4*)io;
        const float4* h04 = (const float4*)h0;
        #pragma unroll
        for (int i = 0; i < 4; ++i) {
            int v = i * 256 + t;
            int tr = v >> 5;
            int q = v & 31;
            int r = base + tr;
            float4 sup = make_float4(0.f, 0.f, 0.f, 0.f);
            if (r < n) {
                float ca = oma * dinv[r];
                float4 a = hacc4[(size_t)r * (D / 4) + q];
                float4 b = h04[(size_t)r * (D / 4) + q];
                sup.x = ca * a.x + alpha * b.x;
                sup.y = ca * a.y + alpha * b.y;
                sup.z = ca * a.z + alpha * b.z;
                sup.w = ca * a.w + alpha * b.w;
            }
            *(float4*)&sSup[tr][q * 4] = sup;
        }
    }
    __syncthreads();

    const int cg = t & 31;
    const int rb = t >> 5;
    float acc[4][4] = {};
    const float4* sW4 = (const float4*)sW;
    #pragma unroll 4
    for (int k = 0; k < D; ++k) {
        float4 w = sW4[k * 32 + cg];
        #pragma unroll
        for (int j = 0; j < 4; ++j) {
            float s = sSup[rb * 4 + j][k];
            acc[j][0] += s * w.x;
            acc[j][1] += s * w.y;
            acc[j][2] += s * w.z;
            acc[j][3] += s * w.w;
        }
    }

    #pragma unroll
    for (int j = 0; j < 4; ++j) {
        int tr = rb * 4 + j;
        int r = base + tr;
        if (r < n) {
            float4 xi = ((const float4*)x)[(size_t)r * (D / 4) + cg];
            float4 sp = *(const float4*)&sSup[tr][cg * 4];
            float4 o;
            o.x = theta * acc[j][0] + omt * sp.x + xi.x;
            o.y = theta * acc[j][1] + omt * sp.y + xi.y;
            o.z = theta * acc[j][2] + omt * sp.z + xi.z;
            o.w = theta * acc[j][3] + omt * sp.w + xi.w;
            ((float4*)io)[(size_t)r * (D / 4) + cg] = o;
        }
    }
}

// ================================ host ===================================

extern "C" void kernel_launch(void* const* d_in, const int* in_sizes, int n_in,
                              void* d_out, int out_size, void* d_ws, size_t ws_size,
                              hipStream_t stream) {
    const float* x = (const float*)d_in[0];
    const int* esrc = (const int*)d_in[1];
    const int* edst = (const int*)d_in[2];
    const float* h0 = (const float*)d_in[3];
    const float* W = (const float*)d_in[4];
    const float* lamda_p = (const float*)d_in[5];
    const float* alpha_p = (const float*)d_in[6];
    const void* l_p = d_in[7];

    const int E = in_sizes[1];
    const int n = in_sizes[0] / D;

    char* w = (char*)d_ws;

    // ---- tier-1 layout ----
    size_t o_deg = 0;                                            // n ints
    size_t o_cnt = ((size_t)n * 4 + 15) & ~15ull;                // 1 int (+pad)
    size_t o_op  = o_cnt + 16;                                   // OCAP int2
    size_t o_xs  = (o_op + (size_t)OCAP * 8 + 15) & ~15ull;      // n*128 bf16
    size_t o_wmt = (o_xs + (size_t)n * 256 + 15) & ~15ull;       // 32 KB
    size_t o_pl  = (o_wmt + 32768 + 15) & ~15ull;                // P_MAX*n ints
    size_t need1 = o_pl + (size_t)P_MAX * n * 4;

    if (ws_size >= need1) {
        int* deg = (int*)(w + o_deg);
        int* cnt = (int*)(w + o_cnt);
        int2* opairs = (int2*)(w + o_op);
        uint4* xs4 = (uint4*)(w + o_xs);
        uint4* wmt = (uint4*)(w + o_wmt);
        int* planes = (int*)(w + o_pl);

        hipMemsetAsync(w, 0, o_cnt + 16, stream);   // deg + cnt

        int chunks = (E + CHUNK - 1) / CHUNK;
        k_prepw2<<<8, 256, 0, stream>>>(W, wmt, lamda_p, l_p);
        k_rank<<<chunks * 8, 256, 0, stream>>>(esrc, edst, deg, planes, cnt,
                                               opairs, E, n);
        k_scale<<<(n * 16 + 255) / 256, 256, 0, stream>>>(
            (const float4*)x, deg, xs4, n);
        k_gather3<<<(n * 16 + 255) / 256, 256, 0, stream>>>(
            xs4, planes, deg, cnt, opairs, h0, alpha_p, (uint4*)d_out, n);
        int ntiles = (n + 15) >> 4;
        k_gemm<<<(ntiles + 3) / 4, 256, 0, stream>>>(
            (float*)d_out, x, wmt, n);
        return;
    }

    // ---- tier-2: old CSR path ----
    const int nb = (n + 1023) / 1024;
    size_t t_deg = 0;
    size_t t_off = (t_deg + (size_t)n * 4 + 15) & ~15ull;
    size_t t_cur = (t_off + (size_t)(n + 1) * 4 + 15) & ~15ull;
    size_t t_bs  = (t_cur + (size_t)n * 4 + 15) & ~15ull;
    size_t t_bo  = (t_bs + (size_t)nb * 4 + 15) & ~15ull;
    size_t t_csr = (t_bo + (size_t)nb * 4 + 15) & ~15ull;
    size_t need2 = t_csr + (size_t)E * 4;

    int* deg = (int*)(w + t_deg);
    float* dinv = (float*)(w + t_deg);

    hipMemsetAsync(deg, 0, (size_t)n * sizeof(int), stream);
    k_deg<<<(E + 255) / 256, 256, 0, stream>>>(edst, deg, E);

    if (ws_size >= need2 && nb <= 1024) {
        int* offsets = (int*)(w + t_off);
        int* cursor  = (int*)(w + t_cur);
        int* bsum    = (int*)(w + t_bs);
        int* boff    = (int*)(w + t_bo);
        int* csr_src = (int*)(w + t_csr);

        k_scan1<<<nb, 256, 0, stream>>>(deg, bsum, n);
        k_scan2<<<1, 64, 0, stream>>>(bsum, boff, offsets, nb, n);
        k_scan3<<<nb, 256, 0, stream>>>(deg, boff, offsets, cursor, n);
        k_csr<<<(E + 255) / 256, 256, 0, stream>>>(esrc, edst, cursor, csr_src, E);
        k_gather<<<((size_t)n * 32 + 255) / 256, 256, 0, stream>>>(
            (const float4*)x, csr_src, offsets, dinv, (float4*)d_out, n);
    } else {
        k_dinv<<<(n + 255) / 256, 256, 0, stream>>>(deg, n);
        hipMemsetAsync(d_out, 0, (size_t)n * D * sizeof(float), stream);
        k_scatter<<<((size_t)E * 32 + 255) / 256, 256, 0, stream>>>(
            (const float4*)x, esrc, edst, dinv, (float*)d_out, E);
    }

    k_final<<<(n + 31) / 32, 256, 0, stream>>>(
        (float*)d_out, dinv, h0, x, W, lamda_p, alpha_p, l_p, n);
}

// Round 7
// 111.379 us; speedup vs baseline: 12.8404x; 1.0447x over previous
//
#include <hip/hip_runtime.h>
#include <math.h>

#define D 128
#define P_MAX 64        // plane capacity (max in-degree before overflow path)
#define OCAP 65536      // overflow edge capacity
#define CHUNK 2048      // edges per chunk in k_rank

using bf16x8 = __attribute__((ext_vector_type(8))) short;
using f32x4  = __attribute__((ext_vector_type(4))) float;

__device__ __forceinline__ float int_or_float(const void* p) {
    int iv = *(const int*)p;
    if (iv > -1000000 && iv < 1000000) return (float)iv;
    return __int_as_float(iv);
}

__device__ __forceinline__ unsigned bf16_rne(float f) {
    unsigned u = __float_as_uint(f);
    return (u + 0x7fffu + ((u >> 16) & 1u)) >> 16;
}
__device__ __forceinline__ unsigned pack_bf2(float a, float b) {
    return bf16_rne(a) | (bf16_rne(b) << 16);
}

// ============================ TIER-1 kernels =============================

// k_rank: deg count + plane-format CSR in one pass, XCD-sliced.
__global__ __launch_bounds__(256) void k_rank(const int* __restrict__ src,
                                              const int* __restrict__ dst,
                                              int* __restrict__ deg,
                                              int* __restrict__ planes,
                                              int* __restrict__ cnt,
                                              int2* __restrict__ opairs,
                                              int E, int n) {
    const int slice = blockIdx.x & 7;
    const int chunk = blockIdx.x >> 3;
    int base = chunk * CHUNK;
    int end = base + CHUNK;
    if (end > E) end = E;
    for (int i = base + threadIdx.x; i < end; i += 256) {
        int t = dst[i];
        if (((t >> 4) & 7) == slice) {
            int s = src[i];
            int rk = atomicAdd(&deg[t], 1);
            if (rk < P_MAX) {
                planes[rk * n + t] = s;
            } else {
                int o = atomicAdd(cnt, 1);
                if (o < OCAP) opairs[o] = make_int2(s, t);
            }
        }
    }
}

// k_scale: xs[r] = bf16(x[r] * dinv[r]) for r<n; xs[n] = 0 (dummy row for
// masked gather). 16 threads/row, 8 elems each.
__global__ __launch_bounds__(256) void k_scale(const float4* __restrict__ x4,
                                               const int* __restrict__ deg,
                                               uint4* __restrict__ xs4, int n) {
    int gid = blockIdx.x * 256 + threadIdx.x;
    int r = gid >> 4;
    if (r > n) return;
    int q = gid & 15;
    if (r == n) {                       // zero dummy row
        xs4[(size_t)r * 16 + q] = make_uint4(0u, 0u, 0u, 0u);
        return;
    }
    int d = deg[r];
    if (d < 1) d = 1;
    float di = rsqrtf((float)d);
    float4 v0 = x4[(size_t)r * 32 + q * 2];
    float4 v1 = x4[(size_t)r * 32 + q * 2 + 1];
    uint4 o;
    o.x = pack_bf2(v0.x * di, v0.y * di);
    o.y = pack_bf2(v0.z * di, v0.w * di);
    o.z = pack_bf2(v1.x * di, v1.y * di);
    o.w = pack_bf2(v1.z * di, v1.w * di);
    xs4[(size_t)r * 16 + q] = o;
}

__device__ __forceinline__ void acc8(float* a, uint4 v) {
    a[0] += __uint_as_float(v.x << 16);
    a[1] += __uint_as_float(v.x & 0xffff0000u);
    a[2] += __uint_as_float(v.y << 16);
    a[3] += __uint_as_float(v.y & 0xffff0000u);
    a[4] += __uint_as_float(v.z << 16);
    a[5] += __uint_as_float(v.z & 0xffff0000u);
    a[6] += __uint_as_float(v.w << 16);
    a[7] += __uint_as_float(v.w & 0xffff0000u);
}

// k_prepw2: Wm = theta*W + (1-theta)*I, bf16, in MFMA B-fragment order:
// entry16B[ct*256 + kb*64 + kg*16 + lc] = Wm^T[ct*16+lc][kb*32+kg*8 ..+8]
__global__ __launch_bounds__(256) void k_prepw2(const float* __restrict__ W,
                                                uint4* __restrict__ wmt,
                                                const float* __restrict__ lamda_p,
                                                const void* __restrict__ l_p) {
    int tid = blockIdx.x * 256 + threadIdx.x;
    if (tid >= 2048) return;
    float lamda = *lamda_p;
    float lf = int_or_float(l_p);
    float theta = logf(lamda / lf + 1.0f);
    float omt = 1.0f - theta;
    int ct = tid >> 8, kb = (tid >> 6) & 3, kg = (tid >> 4) & 3, lc = tid & 15;
    int c = ct * 16 + lc;
    int k0 = kb * 32 + kg * 8;
    float v[8];
    #pragma unroll
    for (int j = 0; j < 8; ++j) {
        float wv = theta * W[(size_t)(k0 + j) * D + c];
        if (k0 + j == c) wv += omt;
        v[j] = wv;
    }
    uint4 o;
    o.x = pack_bf2(v[0], v[1]);
    o.y = pack_bf2(v[2], v[3]);
    o.z = pack_bf2(v[4], v[5]);
    o.w = pack_bf2(v[6], v[7]);
    wmt[tid] = o;
}

// k_fused: gather + support + GEMM + residual in one kernel.
// Block = 256 threads = 4 waves, handles 16 output rows.
// Phase A: 16 groups x 16 lanes gather one row each (masked unroll-8 against
//          the zero dummy row xs[n]), compute support, store bf16 to LDS
//          (uint4-granular XOR swizzle idx^(row&7)).
// Phase B: all 4 waves read the same A-frags from LDS; wave w computes
//          col-tiles {2w, 2w+1} via mfma_f32_16x16x32_bf16; out = acc + x.
__global__ __launch_bounds__(256) void k_fused(
        const uint4* __restrict__ xs4, const int* __restrict__ planes,
        const int* __restrict__ deg, const int* __restrict__ cnt,
        const int2* __restrict__ opairs, const float* __restrict__ h0,
        const float* __restrict__ alpha_p, const uint4* __restrict__ wmt,
        float* __restrict__ out, const float* __restrict__ x, int n) {
    __shared__ uint4 sS[256];           // 16 rows x 256 B, swizzled (4 KB)
    const int t = threadIdx.x;
    const int base = blockIdx.x * 16;

    {
        const int g = t >> 4;           // row group 0..15
        const int q = t & 15;
        int r = base + g;
        int rc = r < n ? r : 0;
        int d = r < n ? deg[rc] : 0;
        int dc = d < P_MAX ? d : P_MAX;
        float a0[8] = {}, a1[8] = {}, a2[8] = {}, a3[8] = {};
        for (int p = 0; p < dc; p += 8) {
            int pi0 = (p + 0 < dc) ? (p + 0) : 0;
            int pi1 = (p + 1 < dc) ? (p + 1) : 0;
            int pi2 = (p + 2 < dc) ? (p + 2) : 0;
            int pi3 = (p + 3 < dc) ? (p + 3) : 0;
            int pi4 = (p + 4 < dc) ? (p + 4) : 0;
            int pi5 = (p + 5 < dc) ? (p + 5) : 0;
            int pi6 = (p + 6 < dc) ? (p + 6) : 0;
            int pi7 = (p + 7 < dc) ? (p + 7) : 0;
            int t0 = planes[(size_t)pi0 * n + rc];
            int t1 = planes[(size_t)pi1 * n + rc];
            int t2 = planes[(size_t)pi2 * n + rc];
            int t3 = planes[(size_t)pi3 * n + rc];
            int t4 = planes[(size_t)pi4 * n + rc];
            int t5 = planes[(size_t)pi5 * n + rc];
            int t6 = planes[(size_t)pi6 * n + rc];
            int t7 = planes[(size_t)pi7 * n + rc];
            int s0 = (p + 0 < dc) ? t0 : n;   // n = zero dummy row
            int s1 = (p + 1 < dc) ? t1 : n;
            int s2 = (p + 2 < dc) ? t2 : n;
            int s3 = (p + 3 < dc) ? t3 : n;
            int s4 = (p + 4 < dc) ? t4 : n;
            int s5 = (p + 5 < dc) ? t5 : n;
            int s6 = (p + 6 < dc) ? t6 : n;
            int s7 = (p + 7 < dc) ? t7 : n;
            uint4 v0 = xs4[(size_t)s0 * 16 + q];
            uint4 v1 = xs4[(size_t)s1 * 16 + q];
            uint4 v2 = xs4[(size_t)s2 * 16 + q];
            uint4 v3 = xs4[(size_t)s3 * 16 + q];
            uint4 v4 = xs4[(size_t)s4 * 16 + q];
            uint4 v5 = xs4[(size_t)s5 * 16 + q];
            uint4 v6 = xs4[(size_t)s6 * 16 + q];
            uint4 v7 = xs4[(size_t)s7 * 16 + q];
            acc8(a0, v0);
            acc8(a1, v1);
            acc8(a2, v2);
            acc8(a3, v3);
            acc8(a0, v4);
            acc8(a1, v5);
            acc8(a2, v6);
            acc8(a3, v7);
        }
        if (d > P_MAX) {                // never taken in practice (cnt == 0)
            int c = *cnt;
            if (c > OCAP) c = OCAP;
            for (int i = 0; i < c; ++i) {
                int2 pr = opairs[i];
                if (pr.y == r) {
                    uint4 v = xs4[(size_t)pr.x * 16 + q];
                    acc8(a0, v);
                }
            }
        }
        float di = rsqrtf((float)(d < 1 ? 1 : d));
        float alpha = *alpha_p;
        float ca = (1.0f - alpha) * di;
        const float4* h04 = (const float4*)h0;
        float4 hb0 = h04[(size_t)rc * 32 + q * 2];
        float4 hb1 = h04[(size_t)rc * 32 + q * 2 + 1];
        float s0 = ca * ((a0[0] + a1[0]) + (a2[0] + a3[0])) + alpha * hb0.x;
        float s1 = ca * ((a0[1] + a1[1]) + (a2[1] + a3[1])) + alpha * hb0.y;
        float s2 = ca * ((a0[2] + a1[2]) + (a2[2] + a3[2])) + alpha * hb0.z;
        float s3 = ca * ((a0[3] + a1[3]) + (a2[3] + a3[3])) + alpha * hb0.w;
        float s4 = ca * ((a0[4] + a1[4]) + (a2[4] + a3[4])) + alpha * hb1.x;
        float s5 = ca * ((a0[5] + a1[5]) + (a2[5] + a3[5])) + alpha * hb1.y;
        float s6 = ca * ((a0[6] + a1[6]) + (a2[6] + a3[6])) + alpha * hb1.z;
        float s7 = ca * ((a0[7] + a1[7]) + (a2[7] + a3[7])) + alpha * hb1.w;
        uint4 o;
        o.x = pack_bf2(s0, s1);
        o.y = pack_bf2(s2, s3);
        o.z = pack_bf2(s4, s5);
        o.w = pack_bf2(s6, s7);
        sS[g * 16 + (q ^ (g & 7))] = o;
    }
    __syncthreads();

    const int lane = t & 63;
    const int wv = t >> 6;              // wave 0..3
    const int lr = lane & 15;
    const int kg = lane >> 4;

    bf16x8 a[4];
    #pragma unroll
    for (int kb = 0; kb < 4; ++kb)
        a[kb] = ((const bf16x8*)sS)[lr * 16 + ((kb * 4 + kg) ^ (lr & 7))];

    const bf16x8* wfr = (const bf16x8*)wmt;
    #pragma unroll
    for (int j = 0; j < 2; ++j) {
        int ct = wv * 2 + j;
        f32x4 acc = (f32x4){0.f, 0.f, 0.f, 0.f};
        #pragma unroll
        for (int kb = 0; kb < 4; ++kb) {
            bf16x8 b = wfr[ct * 256 + kb * 64 + lane];
            acc = __builtin_amdgcn_mfma_f32_16x16x32_bf16(a[kb], b, acc, 0, 0, 0);
        }
        int c = ct * 16 + lr;
        #pragma unroll
        for (int reg = 0; reg < 4; ++reg) {
            int rr = base + kg * 4 + reg;
            if (rr < n) {
                size_t off = (size_t)rr * D + c;
                out[off] = acc[reg] + x[off];
            }
        }
    }
}

// ==================== TIER-2 (old CSR path) kernels ======================

__global__ __launch_bounds__(256) void k_deg(const int* __restrict__ dst,
                                             int* __restrict__ deg, int E) {
    int i = blockIdx.x * 256 + threadIdx.x;
    if (i < E) atomicAdd(&deg[dst[i]], 1);
}

__global__ __launch_bounds__(256) void k_dinv(int* dd, int n) {
    int i = blockIdx.x * 256 + threadIdx.x;
    if (i < n) {
        int d = dd[i];
        if (d < 1) d = 1;
        ((float*)dd)[i] = rsqrtf((float)d);
    }
}

__global__ __launch_bounds__(256) void k_scan1(const int* __restrict__ deg,
                                               int* __restrict__ bsum, int n) {
    __shared__ int red[256];
    int b = blockIdx.x, t = threadIdx.x;
    int base = b * 1024;
    int s = 0;
    #pragma unroll
    for (int i = 0; i < 4; ++i) {
        int idx = base + i * 256 + t;
        if (idx < n) s += deg[idx];
    }
    red[t] = s;
    __syncthreads();
    for (int k = 128; k > 0; k >>= 1) {
        if (t < k) red[t] += red[t + k];
        __syncthreads();
    }
    if (t == 0) bsum[b] = red[0];
}

__global__ void k_scan2(const int* __restrict__ bsum, int* __restrict__ boff,
                        int* __restrict__ offsets, int nb, int n) {
    if (threadIdx.x == 0) {
        int acc = 0;
        for (int i = 0; i < nb; ++i) { boff[i] = acc; acc += bsum[i]; }
        offsets[n] = acc;
    }
}

__global__ __launch_bounds__(256) void k_scan3(int* __restrict__ deg,
                                               const int* __restrict__ boff,
                                               int* __restrict__ offsets,
                                               int* __restrict__ cursor, int n) {
    __shared__ int ls[256];
    int b = blockIdx.x, t = threadIdx.x;
    int base = b * 1024 + t * 4;
    int v[4];
    #pragma unroll
    for (int i = 0; i < 4; ++i) v[i] = (base + i < n) ? deg[base + i] : 0;
    int mysum = v[0] + v[1] + v[2] + v[3];
    ls[t] = mysum;
    __syncthreads();
    for (int k = 1; k < 256; k <<= 1) {
        int add = (t >= k) ? ls[t - k] : 0;
        __syncthreads();
        ls[t] += add;
        __syncthreads();
    }
    int p = boff[b] + ls[t] - mysum;
    #pragma unroll
    for (int i = 0; i < 4; ++i) {
        if (base + i < n) {
            offsets[base + i] = p;
            cursor[base + i] = p;
            int d = v[i] < 1 ? 1 : v[i];
            ((float*)deg)[base + i] = rsqrtf((float)d);
        }
        p += v[i];
    }
}

__global__ __launch_bounds__(256) void k_csr(const int* __restrict__ src,
                                             const int* __restrict__ dst,
                                             int* __restrict__ cursor,
                                             int* __restrict__ csr_src, int E) {
    int i = blockIdx.x * 256 + threadIdx.x;
    if (i < E) {
        int pos = atomicAdd(&cursor[dst[i]], 1);
        csr_src[pos] = src[i];
    }
}

__global__ __launch_bounds__(256) void k_gather(const float4* __restrict__ x4,
                                                const int* __restrict__ csr_src,
                                                const int* __restrict__ offsets,
                                                const float* __restrict__ dinv,
                                                float4* __restrict__ hacc, int n) {
    int idx = blockIdx.x * 256 + threadIdx.x;
    int r = idx >> 5;
    if (r >= n) return;
    int q = idx & 31;
    int e0 = offsets[r], e1 = offsets[r + 1];
    float4 a0 = make_float4(0.f, 0.f, 0.f, 0.f);
    float4 a1 = make_float4(0.f, 0.f, 0.f, 0.f);
    float4 a2 = make_float4(0.f, 0.f, 0.f, 0.f);
    float4 a3 = make_float4(0.f, 0.f, 0.f, 0.f);
    int e = e0;
    for (; e + 4 <= e1; e += 4) {
        int s0 = csr_src[e + 0];
        int s1 = csr_src[e + 1];
        int s2 = csr_src[e + 2];
        int s3 = csr_src[e + 3];
        float c0 = dinv[s0], c1 = dinv[s1], c2 = dinv[s2], c3 = dinv[s3];
        float4 v0 = x4[(size_t)s0 * (D / 4) + q];
        float4 v1 = x4[(size_t)s1 * (D / 4) + q];
        float4 v2 = x4[(size_t)s2 * (D / 4) + q];
        float4 v3 = x4[(size_t)s3 * (D / 4) + q];
        a0.x += v0.x * c0; a0.y += v0.y * c0; a0.z += v0.z * c0; a0.w += v0.w * c0;
        a1.x += v1.x * c1; a1.y += v1.y * c1; a1.z += v1.z * c1; a1.w += v1.w * c1;
        a2.x += v2.x * c2; a2.y += v2.y * c2; a2.z += v2.z * c2; a2.w += v2.w * c2;
        a3.x += v3.x * c3; a3.y += v3.y * c3; a3.z += v3.z * c3; a3.w += v3.w * c3;
    }
    for (; e < e1; ++e) {
        int s = csr_src[e];
        float c = dinv[s];
        float4 v = x4[(size_t)s * (D / 4) + q];
        a0.x += v.x * c; a0.y += v.y * c; a0.z += v.z * c; a0.w += v.w * c;
    }
    float4 acc;
    acc.x = (a0.x + a1.x) + (a2.x + a3.x);
    acc.y = (a0.y + a1.y) + (a2.y + a3.y);
    acc.z = (a0.z + a1.z) + (a2.z + a3.z);
    acc.w = (a0.w + a1.w) + (a2.w + a3.w);
    hacc[(size_t)r * (D / 4) + q] = acc;
}

__global__ __launch_bounds__(256) void k_scatter(const float4* __restrict__ x4,
                                                 const int* __restrict__ src,
                                                 const int* __restrict__ dst,
                                                 const float* __restrict__ dinv,
                                                 float* hacc, int E) {
    int idx = blockIdx.x * 256 + threadIdx.x;
    int e = idx >> 5;
    if (e >= E) return;
    int q = idx & 31;
    int s = src[e];
    int t = dst[e];
    float sc = dinv[s];
    float4 v = x4[(size_t)s * (D / 4) + q];
    float* h = hacc + (size_t)t * D + q * 4;
    unsafeAtomicAdd(h + 0, v.x * sc);
    unsafeAtomicAdd(h + 1, v.y * sc);
    unsafeAtomicAdd(h + 2, v.z * sc);
    unsafeAtomicAdd(h + 3, v.w * sc);
}

// old VALU epilogue (fallback paths)
__global__ __launch_bounds__(256) void k_final(float* io,
                                               const float* __restrict__ dinv,
                                               const float* __restrict__ h0,
                                               const float* __restrict__ x,
                                               const float* __restrict__ W,
                                               const float* __restrict__ lamda_p,
                                               const float* __restrict__ alpha_p,
                                               const void* __restrict__ l_p,
                                               int n) {
    __shared__ float sW[D * D];
    __shared__ float sSup[32][D];
    const int t = threadIdx.x;

    {
        const float4* W4 = (const float4*)W;
        float4* sW4 = (float4*)sW;
        #pragma unroll
        for (int i = 0; i < (D * D / 4) / 256; ++i)
            sW4[i * 256 + t] = W4[i * 256 + t];
    }

    const float alpha = *alpha_p;
    const float lamda = *lamda_p;
    const float lf = int_or_float(l_p);
    const float theta = logf(lamda / lf + 1.0f);
    const float omt = 1.0f - theta;
    const float oma = 1.0f - alpha;

    const int base = blockIdx.x * 32;

    {
        const float4* hacc4 = (const float4*)io;
        const float4* h04 = (const float4*)h0;
        #pragma unroll
        for (int i = 0; i < 4; ++i) {
            int v = i * 256 + t;
            int tr = v >> 5;
            int q = v & 31;
            int r = base + tr;
            float4 sup = make_float4(0.f, 0.f, 0.f, 0.f);
            if (r < n) {
                float ca = oma * dinv[r];
                float4 a = hacc4[(size_t)r * (D / 4) + q];
                float4 b = h04[(size_t)r * (D / 4) + q];
                sup.x = ca * a.x + alpha * b.x;
                sup.y = ca * a.y + alpha * b.y;
                sup.z = ca * a.z + alpha * b.z;
                sup.w = ca * a.w + alpha * b.w;
            }
            *(float4*)&sSup[tr][q * 4] = sup;
        }
    }
    __syncthreads();

    const int cg = t & 31;
    const int rb = t >> 5;
    float acc[4][4] = {};
    const float4* sW4 = (const float4*)sW;
    #pragma unroll 4
    for (int k = 0; k < D; ++k) {
        float4 w = sW4[k * 32 + cg];
        #pragma unroll
        for (int j = 0; j < 4; ++j) {
            float s = sSup[rb * 4 + j][k];
            acc[j][0] += s * w.x;
            acc[j][1] += s * w.y;
            acc[j][2] += s * w.z;
            acc[j][3] += s * w.w;
        }
    }

    #pragma unroll
    for (int j = 0; j < 4; ++j) {
        int tr = rb * 4 + j;
        int r = base + tr;
        if (r < n) {
            float4 xi = ((const float4*)x)[(size_t)r * (D / 4) + cg];
            float4 sp = *(const float4*)&sSup[tr][cg * 4];
            float4 o;
            o.x = theta * acc[j][0] + omt * sp.x + xi.x;
            o.y = theta * acc[j][1] + omt * sp.y + xi.y;
            o.z = theta * acc[j][2] + omt * sp.z + xi.z;
            o.w = theta * acc[j][3] + omt * sp.w + xi.w;
            ((float4*)io)[(size_t)r * (D / 4) + cg] = o;
        }
    }
}

// ================================ host ===================================

extern "C" void kernel_launch(void* const* d_in, const int* in_sizes, int n_in,
                              void* d_out, int out_size, void* d_ws, size_t ws_size,
                              hipStream_t stream) {
    const float* x = (const float*)d_in[0];
    const int* esrc = (const int*)d_in[1];
    const int* edst = (const int*)d_in[2];
    const float* h0 = (const float*)d_in[3];
    const float* W = (const float*)d_in[4];
    const float* lamda_p = (const float*)d_in[5];
    const float* alpha_p = (const float*)d_in[6];
    const void* l_p = d_in[7];

    const int E = in_sizes[1];
    const int n = in_sizes[0] / D;

    char* w = (char*)d_ws;

    // ---- tier-1 layout ----
    size_t o_deg = 0;                                            // n ints
    size_t o_cnt = ((size_t)n * 4 + 15) & ~15ull;                // 1 int (+pad)
    size_t o_op  = o_cnt + 16;                                   // OCAP int2
    size_t o_xs  = (o_op + (size_t)OCAP * 8 + 15) & ~15ull;      // (n+1)*128 bf16
    size_t o_wmt = (o_xs + (size_t)(n + 1) * 256 + 15) & ~15ull; // 32 KB
    size_t o_pl  = (o_wmt + 32768 + 15) & ~15ull;                // P_MAX*n ints
    size_t need1 = o_pl + (size_t)P_MAX * n * 4;

    if (ws_size >= need1) {
        int* deg = (int*)(w + o_deg);
        int* cnt = (int*)(w + o_cnt);
        int2* opairs = (int2*)(w + o_op);
        uint4* xs4 = (uint4*)(w + o_xs);
        uint4* wmt = (uint4*)(w + o_wmt);
        int* planes = (int*)(w + o_pl);

        hipMemsetAsync(w, 0, o_cnt + 16, stream);   // deg + cnt

        int chunks = (E + CHUNK - 1) / CHUNK;
        k_prepw2<<<8, 256, 0, stream>>>(W, wmt, lamda_p, l_p);
        k_rank<<<chunks * 8, 256, 0, stream>>>(esrc, edst, deg, planes, cnt,
                                               opairs, E, n);
        k_scale<<<((n + 1) * 16 + 255) / 256, 256, 0, stream>>>(
            (const float4*)x, deg, xs4, n);
        k_fused<<<(n + 15) / 16, 256, 0, stream>>>(
            xs4, planes, deg, cnt, opairs, h0, alpha_p, wmt,
            (float*)d_out, x, n);
        return;
    }

    // ---- tier-2: old CSR path ----
    const int nb = (n + 1023) / 1024;
    size_t t_deg = 0;
    size_t t_off = (t_deg + (size_t)n * 4 + 15) & ~15ull;
    size_t t_cur = (t_off + (size_t)(n + 1) * 4 + 15) & ~15ull;
    size_t t_bs  = (t_cur + (size_t)n * 4 + 15) & ~15ull;
    size_t t_bo  = (t_bs + (size_t)nb * 4 + 15) & ~15ull;
    size_t t_csr = (t_bo + (size_t)nb * 4 + 15) & ~15ull;
    size_t need2 = t_csr + (size_t)E * 4;

    int* deg = (int*)(w + t_deg);
    float* dinv = (float*)(w + t_deg);

    hipMemsetAsync(deg, 0, (size_t)n * sizeof(int), stream);
    k_deg<<<(E + 255) / 256, 256, 0, stream>>>(edst, deg, E);

    if (ws_size >= need2 && nb <= 1024) {
        int* offsets = (int*)(w + t_off);
        int* cursor  = (int*)(w + t_cur);
        int* bsum    = (int*)(w + t_bs);
        int* boff    = (int*)(w + t_bo);
        int* csr_src = (int*)(w + t_csr);

        k_scan1<<<nb, 256, 0, stream>>>(deg, bsum, n);
        k_scan2<<<1, 64, 0, stream>>>(bsum, boff, offsets, nb, n);
        k_scan3<<<nb, 256, 0, stream>>>(deg, boff, offsets, cursor, n);
        k_csr<<<(E + 255) / 256, 256, 0, stream>>>(esrc, edst, cursor, csr_src, E);
        k_gather<<<((size_t)n * 32 + 255) / 256, 256, 0, stream>>>(
            (const float4*)x, csr_src, offsets, dinv, (float4*)d_out, n);
    } else {
        k_dinv<<<(n + 255) / 256, 256, 0, stream>>>(deg, n);
        hipMemsetAsync(d_out, 0, (size_t)n * D * sizeof(float), stream);
        k_scatter<<<((size_t)E * 32 + 255) / 256, 256, 0, stream>>>(
            (const float4*)x, esrc, edst, dinv, (float*)d_out, E);
    }

    k_final<<<(n + 31) / 32, 256, 0, stream>>>(
        (float*)d_out, dinv, h0, x, W, lamda_p, alpha_p, l_p, n);
}

// Round 8
// 98.779 us; speedup vs baseline: 14.4783x; 1.1276x over previous
//
#include <hip/hip_runtime.h>
#include <math.h>

#define D 128
#define P_MAX 64        // plane capacity (max in-degree before overflow path)
#define OCAP 65536      // overflow edge capacity
#define CHUNK 2048      // edges per chunk in k_rank
#define NSLICE 4        // k_rank dst slices

using bf16x8 = __attribute__((ext_vector_type(8))) short;
using f32x4  = __attribute__((ext_vector_type(4))) float;

__device__ __forceinline__ float int_or_float(const void* p) {
    int iv = *(const int*)p;
    if (iv > -1000000 && iv < 1000000) return (float)iv;
    return __int_as_float(iv);
}

__device__ __forceinline__ unsigned bf16_rne(float f) {
    unsigned u = __float_as_uint(f);
    return (u + 0x7fffu + ((u >> 16) & 1u)) >> 16;
}
__device__ __forceinline__ unsigned pack_bf2(float a, float b) {
    return bf16_rne(a) | (bf16_rne(b) << 16);
}

// ============================ TIER-1 kernels =============================

// k_rank: deg count + plane-format CSR in one pass, dst-sliced (4 slices,
// each handled by blocks on ~2 XCDs for plane-write L2 locality).
__global__ __launch_bounds__(256) void k_rank(const int* __restrict__ src,
                                              const int* __restrict__ dst,
                                              int* __restrict__ deg,
                                              int* __restrict__ planes,
                                              int* __restrict__ cnt,
                                              int2* __restrict__ opairs,
                                              int E, int n) {
    const int slice = blockIdx.x & (NSLICE - 1);
    const int chunk = blockIdx.x / NSLICE;
    int base = chunk * CHUNK;
    int end = base + CHUNK;
    if (end > E) end = E;
    for (int i = base + threadIdx.x; i < end; i += 256) {
        int t = dst[i];
        if (((t >> 4) & (NSLICE - 1)) == slice) {
            int s = src[i];
            int rk = atomicAdd(&deg[t], 1);
            if (rk < P_MAX) {
                planes[rk * n + t] = s;
            } else {
                int o = atomicAdd(cnt, 1);
                if (o < OCAP) opairs[o] = make_int2(s, t);
            }
        }
    }
}

// k_scale8: int8 quantization of x*dinv with per-row scale.
// xs8[r] (128 B) holds biased ubytes q = rn(v*127/rowmax)+128; sxs[r] = rowmax/127.
// Row n is the zero dummy row (scale 0).
__global__ __launch_bounds__(256) void k_scale8(const float4* __restrict__ x4,
                                                const int* __restrict__ deg,
                                                uint2* __restrict__ xs8,
                                                float* __restrict__ sxs, int n) {
    int gid = blockIdx.x * 256 + threadIdx.x;
    int r = gid >> 4;
    if (r > n) return;
    int q = gid & 15;
    if (r == n) {
        xs8[(size_t)r * 16 + q] = make_uint2(0u, 0u);
        if (q == 0) sxs[n] = 0.f;
        return;
    }
    int d = deg[r];
    if (d < 1) d = 1;
    float di = rsqrtf((float)d);
    float4 v0 = x4[(size_t)r * 32 + q * 2];
    float4 v1 = x4[(size_t)r * 32 + q * 2 + 1];
    float f[8] = {v0.x * di, v0.y * di, v0.z * di, v0.w * di,
                  v1.x * di, v1.y * di, v1.z * di, v1.w * di};
    float m = 0.f;
    #pragma unroll
    for (int i = 0; i < 8; ++i) m = fmaxf(m, fabsf(f[i]));
    #pragma unroll
    for (int off = 1; off < 16; off <<= 1)
        m = fmaxf(m, __shfl_xor(m, off, 16));
    float s = m * (1.f / 127.f);
    float rs = m > 0.f ? 127.f / m : 0.f;
    unsigned b[8];
    #pragma unroll
    for (int i = 0; i < 8; ++i)
        b[i] = (unsigned)(__float2int_rn(f[i] * rs) + 128);
    uint2 o;
    o.x = b[0] | (b[1] << 8) | (b[2] << 16) | (b[3] << 24);
    o.y = b[4] | (b[5] << 8) | (b[6] << 16) | (b[7] << 24);
    xs8[(size_t)r * 16 + q] = o;
    if (q == 0) sxs[r] = s;
}

// dequant-accumulate 8 biased ubytes: a[i] += (float)byte_i * s
// (bias correction -128*sum(s) applied once per row at the end)
__device__ __forceinline__ void accq(float* a, uint2 v, float s) {
    a[0] += (float)(v.x & 0xffu) * s;
    a[1] += (float)((v.x >> 8) & 0xffu) * s;
    a[2] += (float)((v.x >> 16) & 0xffu) * s;
    a[3] += (float)(v.x >> 24) * s;
    a[4] += (float)(v.y & 0xffu) * s;
    a[5] += (float)((v.y >> 8) & 0xffu) * s;
    a[6] += (float)((v.y >> 16) & 0xffu) * s;
    a[7] += (float)(v.y >> 24) * s;
}

// k_prepw2: Wm = theta*W + (1-theta)*I, bf16, in MFMA B-fragment order:
// entry16B[ct*256 + kb*64 + kg*16 + lc] = Wm^T[ct*16+lc][kb*32+kg*8 ..+8]
__global__ __launch_bounds__(256) void k_prepw2(const float* __restrict__ W,
                                                uint4* __restrict__ wmt,
                                                const float* __restrict__ lamda_p,
                                                const void* __restrict__ l_p) {
    int tid = blockIdx.x * 256 + threadIdx.x;
    if (tid >= 2048) return;
    float lamda = *lamda_p;
    float lf = int_or_float(l_p);
    float theta = logf(lamda / lf + 1.0f);
    float omt = 1.0f - theta;
    int ct = tid >> 8, kb = (tid >> 6) & 3, kg = (tid >> 4) & 3, lc = tid & 15;
    int c = ct * 16 + lc;
    int k0 = kb * 32 + kg * 8;
    float v[8];
    #pragma unroll
    for (int j = 0; j < 8; ++j) {
        float wv = theta * W[(size_t)(k0 + j) * D + c];
        if (k0 + j == c) wv += omt;
        v[j] = wv;
    }
    uint4 o;
    o.x = pack_bf2(v[0], v[1]);
    o.y = pack_bf2(v[2], v[3]);
    o.z = pack_bf2(v[4], v[5]);
    o.w = pack_bf2(v[6], v[7]);
    wmt[tid] = o;
}

// k_fused: int8 gather + support + MFMA GEMM + residual.
// Block = 256 threads = 4 waves, 16 output rows.
// Phase A: 16 groups x 16 lanes gather one row each (masked unroll-8 against
//          zero dummy row n), dequant-accumulate f32, bias-correct, support
//          -> bf16 LDS (uint4-granular XOR swizzle).
// Phase B: 4 waves read shared A-frags; wave w computes col-tiles {2w,2w+1}
//          via mfma_f32_16x16x32_bf16; out = acc + x.
__global__ __launch_bounds__(256) void k_fused(
        const uint2* __restrict__ xs8, const float* __restrict__ sxs,
        const int* __restrict__ planes, const int* __restrict__ deg,
        const int* __restrict__ cnt, const int2* __restrict__ opairs,
        const float* __restrict__ h0, const float* __restrict__ alpha_p,
        const uint4* __restrict__ wmt, float* __restrict__ out,
        const float* __restrict__ x, int n) {
    __shared__ uint4 sS[256];           // 16 rows x 256 B, swizzled (4 KB)
    const int t = threadIdx.x;
    const int base = blockIdx.x * 16;

    {
        const int g = t >> 4;           // row group 0..15
        const int q = t & 15;
        int r = base + g;
        int rc = r < n ? r : 0;
        int d = r < n ? deg[rc] : 0;
        int dc = d < P_MAX ? d : P_MAX;
        float a0[8] = {}, a1[8] = {}, a2[8] = {}, a3[8] = {};
        float ssum = 0.f;
        for (int p = 0; p < dc; p += 8) {
            int pi0 = (p + 0 < dc) ? (p + 0) : 0;
            int pi1 = (p + 1 < dc) ? (p + 1) : 0;
            int pi2 = (p + 2 < dc) ? (p + 2) : 0;
            int pi3 = (p + 3 < dc) ? (p + 3) : 0;
            int pi4 = (p + 4 < dc) ? (p + 4) : 0;
            int pi5 = (p + 5 < dc) ? (p + 5) : 0;
            int pi6 = (p + 6 < dc) ? (p + 6) : 0;
            int pi7 = (p + 7 < dc) ? (p + 7) : 0;
            int t0 = planes[(size_t)pi0 * n + rc];
            int t1 = planes[(size_t)pi1 * n + rc];
            int t2 = planes[(size_t)pi2 * n + rc];
            int t3 = planes[(size_t)pi3 * n + rc];
            int t4 = planes[(size_t)pi4 * n + rc];
            int t5 = planes[(size_t)pi5 * n + rc];
            int t6 = planes[(size_t)pi6 * n + rc];
            int t7 = planes[(size_t)pi7 * n + rc];
            int s0 = (p + 0 < dc) ? t0 : n;   // n = zero dummy row (scale 0)
            int s1 = (p + 1 < dc) ? t1 : n;
            int s2 = (p + 2 < dc) ? t2 : n;
            int s3 = (p + 3 < dc) ? t3 : n;
            int s4 = (p + 4 < dc) ? t4 : n;
            int s5 = (p + 5 < dc) ? t5 : n;
            int s6 = (p + 6 < dc) ? t6 : n;
            int s7 = (p + 7 < dc) ? t7 : n;
            float c0 = sxs[s0], c1 = sxs[s1], c2 = sxs[s2], c3 = sxs[s3];
            float c4 = sxs[s4], c5 = sxs[s5], c6 = sxs[s6], c7 = sxs[s7];
            uint2 v0 = xs8[(size_t)s0 * 16 + q];
            uint2 v1 = xs8[(size_t)s1 * 16 + q];
            uint2 v2 = xs8[(size_t)s2 * 16 + q];
            uint2 v3 = xs8[(size_t)s3 * 16 + q];
            uint2 v4 = xs8[(size_t)s4 * 16 + q];
            uint2 v5 = xs8[(size_t)s5 * 16 + q];
            uint2 v6 = xs8[(size_t)s6 * 16 + q];
            uint2 v7 = xs8[(size_t)s7 * 16 + q];
            accq(a0, v0, c0);
            accq(a1, v1, c1);
            accq(a2, v2, c2);
            accq(a3, v3, c3);
            accq(a0, v4, c4);
            accq(a1, v5, c5);
            accq(a2, v6, c6);
            accq(a3, v7, c7);
            ssum += ((c0 + c1) + (c2 + c3)) + ((c4 + c5) + (c6 + c7));
        }
        if (d > P_MAX) {                // never taken in practice (cnt == 0)
            int c = *cnt;
            if (c > OCAP) c = OCAP;
            for (int i = 0; i < c; ++i) {
                int2 pr = opairs[i];
                if (pr.y == r) {
                    float cs = sxs[pr.x];
                    uint2 v = xs8[(size_t)pr.x * 16 + q];
                    accq(a0, v, cs);
                    ssum += cs;
                }
            }
        }
        float di = rsqrtf((float)(d < 1 ? 1 : d));
        float alpha = *alpha_p;
        float ca = (1.0f - alpha) * di;
        float corr = 128.f * ssum;
        const float4* h04 = (const float4*)h0;
        float4 hb0 = h04[(size_t)rc * 32 + q * 2];
        float4 hb1 = h04[(size_t)rc * 32 + q * 2 + 1];
        float s0 = ca * (((a0[0] + a1[0]) + (a2[0] + a3[0])) - corr) + alpha * hb0.x;
        float s1 = ca * (((a0[1] + a1[1]) + (a2[1] + a3[1])) - corr) + alpha * hb0.y;
        float s2 = ca * (((a0[2] + a1[2]) + (a2[2] + a3[2])) - corr) + alpha * hb0.z;
        float s3 = ca * (((a0[3] + a1[3]) + (a2[3] + a3[3])) - corr) + alpha * hb0.w;
        float s4 = ca * (((a0[4] + a1[4]) + (a2[4] + a3[4])) - corr) + alpha * hb1.x;
        float s5 = ca * (((a0[5] + a1[5]) + (a2[5] + a3[5])) - corr) + alpha * hb1.y;
        float s6 = ca * (((a0[6] + a1[6]) + (a2[6] + a3[6])) - corr) + alpha * hb1.z;
        float s7 = ca * (((a0[7] + a1[7]) + (a2[7] + a3[7])) - corr) + alpha * hb1.w;
        uint4 o;
        o.x = pack_bf2(s0, s1);
        o.y = pack_bf2(s2, s3);
        o.z = pack_bf2(s4, s5);
        o.w = pack_bf2(s6, s7);
        sS[g * 16 + (q ^ (g & 7))] = o;
    }
    __syncthreads();

    const int lane = t & 63;
    const int wv = t >> 6;              // wave 0..3
    const int lr = lane & 15;
    const int kg = lane >> 4;

    bf16x8 a[4];
    #pragma unroll
    for (int kb = 0; kb < 4; ++kb)
        a[kb] = ((const bf16x8*)sS)[lr * 16 + ((kb * 4 + kg) ^ (lr & 7))];

    const bf16x8* wfr = (const bf16x8*)wmt;
    #pragma unroll
    for (int j = 0; j < 2; ++j) {
        int ct = wv * 2 + j;
        f32x4 acc = (f32x4){0.f, 0.f, 0.f, 0.f};
        #pragma unroll
        for (int kb = 0; kb < 4; ++kb) {
            bf16x8 b = wfr[ct * 256 + kb * 64 + lane];
            acc = __builtin_amdgcn_mfma_f32_16x16x32_bf16(a[kb], b, acc, 0, 0, 0);
        }
        int c = ct * 16 + lr;
        #pragma unroll
        for (int reg = 0; reg < 4; ++reg) {
            int rr = base + kg * 4 + reg;
            if (rr < n) {
                size_t off = (size_t)rr * D + c;
                out[off] = acc[reg] + x[off];
            }
        }
    }
}

// ==================== TIER-2 (old CSR path) kernels ======================

__global__ __launch_bounds__(256) void k_deg(const int* __restrict__ dst,
                                             int* __restrict__ deg, int E) {
    int i = blockIdx.x * 256 + threadIdx.x;
    if (i < E) atomicAdd(&deg[dst[i]], 1);
}

__global__ __launch_bounds__(256) void k_dinv(int* dd, int n) {
    int i = blockIdx.x * 256 + threadIdx.x;
    if (i < n) {
        int d = dd[i];
        if (d < 1) d = 1;
        ((float*)dd)[i] = rsqrtf((float)d);
    }
}

__global__ __launch_bounds__(256) void k_scan1(const int* __restrict__ deg,
                                               int* __restrict__ bsum, int n) {
    __shared__ int red[256];
    int b = blockIdx.x, t = threadIdx.x;
    int base = b * 1024;
    int s = 0;
    #pragma unroll
    for (int i = 0; i < 4; ++i) {
        int idx = base + i * 256 + t;
        if (idx < n) s += deg[idx];
    }
    red[t] = s;
    __syncthreads();
    for (int k = 128; k > 0; k >>= 1) {
        if (t < k) red[t] += red[t + k];
        __syncthreads();
    }
    if (t == 0) bsum[b] = red[0];
}

__global__ void k_scan2(const int* __restrict__ bsum, int* __restrict__ boff,
                        int* __restrict__ offsets, int nb, int n) {
    if (threadIdx.x == 0) {
        int acc = 0;
        for (int i = 0; i < nb; ++i) { boff[i] = acc; acc += bsum[i]; }
        offsets[n] = acc;
    }
}

__global__ __launch_bounds__(256) void k_scan3(int* __restrict__ deg,
                                               const int* __restrict__ boff,
                                               int* __restrict__ offsets,
                                               int* __restrict__ cursor, int n) {
    __shared__ int ls[256];
    int b = blockIdx.x, t = threadIdx.x;
    int base = b * 1024 + t * 4;
    int v[4];
    #pragma unroll
    for (int i = 0; i < 4; ++i) v[i] = (base + i < n) ? deg[base + i] : 0;
    int mysum = v[0] + v[1] + v[2] + v[3];
    ls[t] = mysum;
    __syncthreads();
    for (int k = 1; k < 256; k <<= 1) {
        int add = (t >= k) ? ls[t - k] : 0;
        __syncthreads();
        ls[t] += add;
        __syncthreads();
    }
    int p = boff[b] + ls[t] - mysum;
    #pragma unroll
    for (int i = 0; i < 4; ++i) {
        if (base + i < n) {
            offsets[base + i] = p;
            cursor[base + i] = p;
            int d = v[i] < 1 ? 1 : v[i];
            ((float*)deg)[base + i] = rsqrtf((float)d);
        }
        p += v[i];
    }
}

__global__ __launch_bounds__(256) void k_csr(const int* __restrict__ src,
                                             const int* __restrict__ dst,
                                             int* __restrict__ cursor,
                                             int* __restrict__ csr_src, int E) {
    int i = blockIdx.x * 256 + threadIdx.x;
    if (i < E) {
        int pos = atomicAdd(&cursor[dst[i]], 1);
        csr_src[pos] = src[i];
    }
}

__global__ __launch_bounds__(256) void k_gather(const float4* __restrict__ x4,
                                                const int* __restrict__ csr_src,
                                                const int* __restrict__ offsets,
                                                const float* __restrict__ dinv,
                                                float4* __restrict__ hacc, int n) {
    int idx = blockIdx.x * 256 + threadIdx.x;
    int r = idx >> 5;
    if (r >= n) return;
    int q = idx & 31;
    int e0 = offsets[r], e1 = offsets[r + 1];
    float4 a0 = make_float4(0.f, 0.f, 0.f, 0.f);
    float4 a1 = make_float4(0.f, 0.f, 0.f, 0.f);
    float4 a2 = make_float4(0.f, 0.f, 0.f, 0.f);
    float4 a3 = make_float4(0.f, 0.f, 0.f, 0.f);
    int e = e0;
    for (; e + 4 <= e1; e += 4) {
        int s0 = csr_src[e + 0];
        int s1 = csr_src[e + 1];
        int s2 = csr_src[e + 2];
        int s3 = csr_src[e + 3];
        float c0 = dinv[s0], c1 = dinv[s1], c2 = dinv[s2], c3 = dinv[s3];
        float4 v0 = x4[(size_t)s0 * (D / 4) + q];
        float4 v1 = x4[(size_t)s1 * (D / 4) + q];
        float4 v2 = x4[(size_t)s2 * (D / 4) + q];
        float4 v3 = x4[(size_t)s3 * (D / 4) + q];
        a0.x += v0.x * c0; a0.y += v0.y * c0; a0.z += v0.z * c0; a0.w += v0.w * c0;
        a1.x += v1.x * c1; a1.y += v1.y * c1; a1.z += v1.z * c1; a1.w += v1.w * c1;
        a2.x += v2.x * c2; a2.y += v2.y * c2; a2.z += v2.z * c2; a2.w += v2.w * c2;
        a3.x += v3.x * c3; a3.y += v3.y * c3; a3.z += v3.z * c3; a3.w += v3.w * c3;
    }
    for (; e < e1; ++e) {
        int s = csr_src[e];
        float c = dinv[s];
        float4 v = x4[(size_t)s * (D / 4) + q];
        a0.x += v.x * c; a0.y += v.y * c; a0.z += v.z * c; a0.w += v.w * c;
    }
    float4 acc;
    acc.x = (a0.x + a1.x) + (a2.x + a3.x);
    acc.y = (a0.y + a1.y) + (a2.y + a3.y);
    acc.z = (a0.z + a1.z) + (a2.z + a3.z);
    acc.w = (a0.w + a1.w) + (a2.w + a3.w);
    hacc[(size_t)r * (D / 4) + q] = acc;
}

__global__ __launch_bounds__(256) void k_scatter(const float4* __restrict__ x4,
                                                 const int* __restrict__ src,
                                                 const int* __restrict__ dst,
                                                 const float* __restrict__ dinv,
                                                 float* hacc, int E) {
    int idx = blockIdx.x * 256 + threadIdx.x;
    int e = idx >> 5;
    if (e >= E) return;
    int q = idx & 31;
    int s = src[e];
    int t = dst[e];
    float sc = dinv[s];
    float4 v = x4[(size_t)s * (D / 4) + q];
    float* h = hacc + (size_t)t * D + q * 4;
    unsafeAtomicAdd(h + 0, v.x * sc);
    unsafeAtomicAdd(h + 1, v.y * sc);
    unsafeAtomicAdd(h + 2, v.z * sc);
    unsafeAtomicAdd(h + 3, v.w * sc);
}

// old VALU epilogue (fallback paths)
__global__ __launch_bounds__(256) void k_final(float* io,
                                               const float* __restrict__ dinv,
                                               const float* __restrict__ h0,
                                               const float* __restrict__ x,
                                               const float* __restrict__ W,
                                               const float* __restrict__ lamda_p,
                                               const float* __restrict__ alpha_p,
                                               const void* __restrict__ l_p,
                                               int n) {
    __shared__ float sW[D * D];
    __shared__ float sSup[32][D];
    const int t = threadIdx.x;

    {
        const float4* W4 = (const float4*)W;
        float4* sW4 = (float4*)sW;
        #pragma unroll
        for (int i = 0; i < (D * D / 4) / 256; ++i)
            sW4[i * 256 + t] = W4[i * 256 + t];
    }

    const float alpha = *alpha_p;
    const float lamda = *lamda_p;
    const float lf = int_or_float(l_p);
    const float theta = logf(lamda / lf + 1.0f);
    const float omt = 1.0f - theta;
    const float oma = 1.0f - alpha;

    const int base = blockIdx.x * 32;

    {
        const float4* hacc4 = (const float4*)io;
        const float4* h04 = (const float4*)h0;
        #pragma unroll
        for (int i = 0; i < 4; ++i) {
            int v = i * 256 + t;
            int tr = v >> 5;
            int q = v & 31;
            int r = base + tr;
            float4 sup = make_float4(0.f, 0.f, 0.f, 0.f);
            if (r < n) {
                float ca = oma * dinv[r];
                float4 a = hacc4[(size_t)r * (D / 4) + q];
                float4 b = h04[(size_t)r * (D / 4) + q];
                sup.x = ca * a.x + alpha * b.x;
                sup.y = ca * a.y + alpha * b.y;
                sup.z = ca * a.z + alpha * b.z;
                sup.w = ca * a.w + alpha * b.w;
            }
            *(float4*)&sSup[tr][q * 4] = sup;
        }
    }
    __syncthreads();

    const int cg = t & 31;
    const int rb = t >> 5;
    float acc[4][4] = {};
    const float4* sW4 = (const float4*)sW;
    #pragma unroll 4
    for (int k = 0; k < D; ++k) {
        float4 w = sW4[k * 32 + cg];
        #pragma unroll
        for (int j = 0; j < 4; ++j) {
            float s = sSup[rb * 4 + j][k];
            acc[j][0] += s * w.x;
            acc[j][1] += s * w.y;
            acc[j][2] += s * w.z;
            acc[j][3] += s * w.w;
        }
    }

    #pragma unroll
    for (int j = 0; j < 4; ++j) {
        int tr = rb * 4 + j;
        int r = base + tr;
        if (r < n) {
            float4 xi = ((const float4*)x)[(size_t)r * (D / 4) + cg];
            float4 sp = *(const float4*)&sSup[tr][cg * 4];
            float4 o;
            o.x = theta * acc[j][0] + omt * sp.x + xi.x;
            o.y = theta * acc[j][1] + omt * sp.y + xi.y;
            o.z = theta * acc[j][2] + omt * sp.z + xi.z;
            o.w = theta * acc[j][3] + omt * sp.w + xi.w;
            ((float4*)io)[(size_t)r * (D / 4) + cg] = o;
        }
    }
}

// ================================ host ===================================

extern "C" void kernel_launch(void* const* d_in, const int* in_sizes, int n_in,
                              void* d_out, int out_size, void* d_ws, size_t ws_size,
                              hipStream_t stream) {
    const float* x = (const float*)d_in[0];
    const int* esrc = (const int*)d_in[1];
    const int* edst = (const int*)d_in[2];
    const float* h0 = (const float*)d_in[3];
    const float* W = (const float*)d_in[4];
    const float* lamda_p = (const float*)d_in[5];
    const float* alpha_p = (const float*)d_in[6];
    const void* l_p = d_in[7];

    const int E = in_sizes[1];
    const int n = in_sizes[0] / D;

    char* w = (char*)d_ws;

    // ---- tier-1 layout ----
    size_t o_deg = 0;                                            // n ints
    size_t o_cnt = ((size_t)n * 4 + 15) & ~15ull;                // 1 int (+pad)
    size_t o_op  = o_cnt + 16;                                   // OCAP int2
    size_t o_x8  = (o_op + (size_t)OCAP * 8 + 15) & ~15ull;      // (n+1)*128 u8
    size_t o_sx  = (o_x8 + (size_t)(n + 1) * 128 + 15) & ~15ull; // (n+1) floats
    size_t o_wmt = (o_sx + (size_t)(n + 1) * 4 + 15) & ~15ull;   // 32 KB
    size_t o_pl  = (o_wmt + 32768 + 15) & ~15ull;                // P_MAX*n ints
    size_t need1 = o_pl + (size_t)P_MAX * n * 4;

    if (ws_size >= need1) {
        int* deg = (int*)(w + o_deg);
        int* cnt = (int*)(w + o_cnt);
        int2* opairs = (int2*)(w + o_op);
        uint2* xs8 = (uint2*)(w + o_x8);
        float* sxs = (float*)(w + o_sx);
        uint4* wmt = (uint4*)(w + o_wmt);
        int* planes = (int*)(w + o_pl);

        hipMemsetAsync(w, 0, o_cnt + 16, stream);   // deg + cnt

        int chunks = (E + CHUNK - 1) / CHUNK;
        k_prepw2<<<8, 256, 0, stream>>>(W, wmt, lamda_p, l_p);
        k_rank<<<chunks * NSLICE, 256, 0, stream>>>(esrc, edst, deg, planes,
                                                    cnt, opairs, E, n);
        k_scale8<<<((n + 1) * 16 + 255) / 256, 256, 0, stream>>>(
            (const float4*)x, deg, xs8, sxs, n);
        k_fused<<<(n + 15) / 16, 256, 0, stream>>>(
            xs8, sxs, planes, deg, cnt, opairs, h0, alpha_p, wmt,
            (float*)d_out, x, n);
        return;
    }

    // ---- tier-2: old CSR path ----
    const int nb = (n + 1023) / 1024;
    size_t t_deg = 0;
    size_t t_off = (t_deg + (size_t)n * 4 + 15) & ~15ull;
    size_t t_cur = (t_off + (size_t)(n + 1) * 4 + 15) & ~15ull;
    size_t t_bs  = (t_cur + (size_t)n * 4 + 15) & ~15ull;
    size_t t_bo  = (t_bs + (size_t)nb * 4 + 15) & ~15ull;
    size_t t_csr = (t_bo + (size_t)nb * 4 + 15) & ~15ull;
    size_t need2 = t_csr + (size_t)E * 4;

    int* deg = (int*)(w + t_deg);
    float* dinv = (float*)(w + t_deg);

    hipMemsetAsync(deg, 0, (size_t)n * sizeof(int), stream);
    k_deg<<<(E + 255) / 256, 256, 0, stream>>>(edst, deg, E);

    if (ws_size >= need2 && nb <= 1024) {
        int* offsets = (int*)(w + t_off);
        int* cursor  = (int*)(w + t_cur);
        int* bsum    = (int*)(w + t_bs);
        int* boff    = (int*)(w + t_bo);
        int* csr_src = (int*)(w + t_csr);

        k_scan1<<<nb, 256, 0, stream>>>(deg, bsum, n);
        k_scan2<<<1, 64, 0, stream>>>(bsum, boff, offsets, nb, n);
        k_scan3<<<nb, 256, 0, stream>>>(deg, boff, offsets, cursor, n);
        k_csr<<<(E + 255) / 256, 256, 0, stream>>>(esrc, edst, cursor, csr_src, E);
        k_gather<<<((size_t)n * 32 + 255) / 256, 256, 0, stream>>>(
            (const float4*)x, csr_src, offsets, dinv, (float4*)d_out, n);
    } else {
        k_dinv<<<(n + 255) / 256, 256, 0, stream>>>(deg, n);
        hipMemsetAsync(d_out, 0, (size_t)n * D * sizeof(float), stream);
        k_scatter<<<((size_t)E * 32 + 255) / 256, 256, 0, stream>>>(
            (const float4*)x, esrc, edst, dinv, (float*)d_out, E);
    }

    k_final<<<(n + 31) / 32, 256, 0, stream>>>(
        (float*)d_out, dinv, h0, x, W, lamda_p, alpha_p, l_p, n);
}